// Round 4
// baseline (222.554 us; speedup 1.0000x reference)
//
#include <hip/hip_runtime.h>
#include <math.h>

#define NN 64      // nodes per graph
#define HH 128     // hidden channels
#define NBB 8      // bessel basis
#define TT 32      // time embedding dim
#define BB 64      // batch
#define NROW (BB * NN)        // 4096 total rows
#define PLANE ((size_t)NROW * HH)   // 524288
#define WR1OFF (8 * 16384)    // Wr1 B-frag slabs in Wpack (2 x 4096)

typedef __attribute__((ext_vector_type(8))) short short8;
typedef __attribute__((ext_vector_type(4))) float f32x4;
typedef __attribute__((ext_vector_type(2))) float f32x2;
typedef __attribute__((ext_vector_type(2))) unsigned int u32x2;

__device__ __forceinline__ float silu_f(float x) {
  return x * __builtin_amdgcn_rcpf(1.0f + __expf(-x));
}

__device__ __forceinline__ unsigned short bf1(float x) {
  __bf16 h = (__bf16)x;
  return *(unsigned short*)&h;
}
__device__ __forceinline__ unsigned bf2(float lo, float hi) {
  return (unsigned)bf1(lo) | ((unsigned)bf1(hi) << 16);
}

// 8-row MFMA GEMM tile: A rows 8..15 zero. C map: row=quad*4+reg (<8), col=w*32+nt*16+nlo.
__device__ __forceinline__ void gemm8(
    const unsigned short (*sA)[136], const unsigned short* __restrict__ Bp,
    int w, int nlo, int quad, f32x4 C[2]) {
  const short8 z8 = {0, 0, 0, 0, 0, 0, 0, 0};
  short8 afr[4];
#pragma unroll
  for (int kt = 0; kt < 4; ++kt)
    afr[kt] = (nlo < 8) ? *(const short8*)&sA[nlo][kt * 32 + quad * 8] : z8;
#pragma unroll
  for (int nt = 0; nt < 2; ++nt)
#pragma unroll
    for (int kt = 0; kt < 4; ++kt) {
      short8 bfr = *(const short8*)&Bp[((kt * 128 + w * 32 + nt * 16 + nlo) * 4 + quad) * 8];
      C[nt] = __builtin_amdgcn_mfma_f32_16x16x32_bf16(afr[kt], bfr, C[nt], 0, 0, 0);
    }
}

// Grid 256. Pack all weights -> bf16 MFMA-B-frag order (coalesced writes, gathered
// reads); blocks<64 also init h.
__global__ __launch_bounds__(256) void k_init(
    const float* __restrict__ emb, const int* __restrict__ z,
    const float* __restrict__ gf, const float* __restrict__ Wt,
    const float* __restrict__ Wr1, const float* __restrict__ Wr2,
    const float* __restrict__ Wupd, const float* __restrict__ Wmix,
    const float* __restrict__ Wg1, const float* __restrict__ Wg2,
    float* __restrict__ h, unsigned short* __restrict__ Wpack) {
  __shared__ float tvec[HH];
  __shared__ int sz[NN];
  int b4 = blockIdx.x, tid = threadIdx.x;
  {
    // thread <-> output dword: p2 in [0,65536); p = output ushort index (even)
    int p2 = b4 * 256 + tid;
    int p = p2 * 2;
    int m = p >> 14;                 // matrix 0..7
    int j = p & 7;                   // 0,2,4,6 (handles j and j+1)
    int q = (p >> 3) & 3;
    int n = (p >> 5) & 127;
    int kt = (p >> 12) & 3;
    int k = kt * 32 + q * 8 + j;     // source row; pair (k, k+1)
    const float* src;
    int base;
    if (m < 2) { src = Wr2; base = m * 16384; }
    else if (m < 4) { src = Wupd; base = (m - 2) * 16384; }
    else if (m < 6) { src = Wmix; base = (m - 4) * 16384; }
    else if (m == 6) { src = Wg1; base = 0; }
    else { src = Wg2; base = 0; }
    float v0 = src[base + k * 128 + n];
    float v1 = src[base + (k + 1) * 128 + n];
    *(unsigned*)&Wpack[p] = bf2(v0, v1);
  }
  if (tid < 32) {                           // Wr1 zero-padded B-frags
    int e = b4 * 32 + tid;                  // 0..8191
    int l = e >> 12, p = e & 4095;          // p = (n*4+q)*8+j
    int n = p >> 5, q = (p >> 3) & 3, j = p & 7;
    float val = (q == 0) ? Wr1[l * NBB * HH + j * HH + n] : 0.f;
    Wpack[WR1OFF + l * 4096 + p] = bf1(val);
  }
  if (b4 < 64) {
    int b = b4;
    if (tid < NN) sz[tid] = z[b * NN + tid];
    if (tid < HH) {
      float acc = 0.f;
#pragma unroll
      for (int k = 0; k < TT; ++k) acc += gf[b * TT + k] * Wt[k * HH + tid];
      tvec[tid] = acc;
    }
    __syncthreads();
    for (int i = tid; i < NN * HH; i += 256) {
      int n = i >> 7, c = i & 127;
      h[(size_t)b * NN * HH + i] = emb[sz[n] * HH + c] + tvec[c];
    }
  }
}

// One block (256 thr = 4 waves) per (b, receiver-quad {4rp..4rp+3}), as two pairs.
// sh_S double-buffered: StageB(ri+1) overlaps main-GEMM(ri). Epilogue a0/a1 via
// in-register shuffle reduction (no M0T tile, no U-GEMM). LDS 38912 B -> 4 blk/CU.
__global__ __launch_bounds__(256, 4) void k_layer(
    const float* __restrict__ pos,
    const float* __restrict__ hA,
    const unsigned short* __restrict__ a0in,   // bf16 plane 0 (l=1 only)
    unsigned short* __restrict__ apout,        // bf16 planes
    const unsigned short* __restrict__ Wpack,
    int l) {
  __shared__ __align__(16) unsigned short sh_S[2][NN][136];  // 34816 B (buf0 = a0 tile)
  __shared__ __align__(16) unsigned short sh_rbh[2][NN][8];  // 2048 B
  __shared__ __align__(16) float sh_uf[2][NN][4];            // 2048 B: u/63 (f32)

  int blk = blockIdx.x;          // b*16 + rp4
  int b = blk >> 4, rp4 = blk & 15;
  int r0 = rp4 * 4;
  int tid = threadIdx.x;
  int w = tid >> 6, lane = tid & 63;
  int nlo = lane & 15, quad = lane >> 4;
  const float invAvg = 1.0f / 63.0f;

  // ---- hbv base prefetch from hA (C-reg layout) ----
  f32x4 hbv[4][2];
#pragma unroll
  for (int mt = 0; mt < 4; ++mt)
#pragma unroll
    for (int nt = 0; nt < 2; ++nt)
#pragma unroll
      for (int reg = 0; reg < 4; ++reg)
        hbv[mt][nt][reg] =
            hA[((size_t)b * NN + mt * 16 + quad * 4 + reg) * HH + w * 32 + nt * 16 + nlo];

  // ---- hoisted fragment loads (L2-hot, shared by all 4 receivers) ----
  const unsigned short* Wr1p = Wpack + WR1OFF + l * 4096;
  short8 bw[2];
#pragma unroll
  for (int nt = 0; nt < 2; ++nt)
    bw[nt] = *(const short8*)&Wr1p[((w * 32 + nt * 16 + nlo) * 4 + quad) * 8];
  const unsigned short* Bbase = Wpack + l * 16384;
  short8 bfr[4][2];
#pragma unroll
  for (int kt = 0; kt < 4; ++kt)
#pragma unroll
    for (int nt = 0; nt < 2; ++nt)
      bfr[kt][nt] = *(const short8*)&Bbase[((kt * 128 + w * 32 + nt * 16 + nlo) * 4 + quad) * 8];

  const short8 zero8 = {0, 0, 0, 0, 0, 0, 0, 0};

  // StageB: S_ri = silu(rb_ri @ Wr1) -> sh_S[buf]
  auto stageB = [&](int ri, int buf) {
#pragma unroll
    for (int mtp = 0; mtp < 2; ++mtp) {
      f32x4 Cs[2][2];
#pragma unroll
      for (int mi = 0; mi < 2; ++mi)
#pragma unroll
        for (int nt = 0; nt < 2; ++nt) Cs[mi][nt] = (f32x4){0.f, 0.f, 0.f, 0.f};
#pragma unroll
      for (int mi = 0; mi < 2; ++mi) {
        int mt = mtp * 2 + mi;
        short8 afr = (quad == 0) ? *(const short8*)&sh_rbh[ri][mt * 16 + nlo][0] : zero8;
#pragma unroll
        for (int nt = 0; nt < 2; ++nt)
          Cs[mi][nt] = __builtin_amdgcn_mfma_f32_16x16x32_bf16(afr, bw[nt], Cs[mi][nt], 0, 0, 0);
      }
#pragma unroll
      for (int mi = 0; mi < 2; ++mi)
#pragma unroll
        for (int nt = 0; nt < 2; ++nt)
#pragma unroll
          for (int reg = 0; reg < 4; ++reg) {
            int s = (mtp * 2 + mi) * 16 + quad * 4 + reg;
            int c = w * 32 + nt * 16 + nlo;
            sh_S[buf][s][c] = bf1(silu_f(Cs[mi][nt][reg]));
          }
    }
  };

  // Main GEMM + in-register a0/a1 reduction for receiver rb0+ri reading sh_S[buf].
  auto mainG = [&](int ri, int buf, int rglob) {
    float a0[2] = {0.f, 0.f};
    float a1[2][3] = {{0.f, 0.f, 0.f}, {0.f, 0.f, 0.f}};
#pragma unroll
    for (int mt = 0; mt < 4; ++mt) {
      short8 afr[4];
      int s_a = mt * 16 + nlo;
#pragma unroll
      for (int kt = 0; kt < 4; ++kt)
        afr[kt] = *(const short8*)&sh_S[buf][s_a][kt * 32 + quad * 8];
      f32x4 u3[4];
#pragma unroll
      for (int reg = 0; reg < 4; ++reg)
        u3[reg] = *(const f32x4*)&sh_uf[ri][mt * 16 + quad * 4 + reg][0];
#pragma unroll
      for (int nt = 0; nt < 2; ++nt) {
        f32x4 C = {0.f, 0.f, 0.f, 0.f};
#pragma unroll
        for (int kt = 0; kt < 4; ++kt)
          C = __builtin_amdgcn_mfma_f32_16x16x32_bf16(afr[kt], bfr[kt][nt], C, 0, 0, 0);
#pragma unroll
        for (int reg = 0; reg < 4; ++reg) {
          float m0 = C[reg] * hbv[mt][nt][reg];
          a0[nt] += m0;
          a1[nt][0] += u3[reg][0] * m0;
          a1[nt][1] += u3[reg][1] * m0;
          a1[nt][2] += u3[reg][2] * m0;
        }
      }
    }
    // reduce over quads (rows) and store; cols = w*32+nt*16+nlo
#pragma unroll
    for (int nt = 0; nt < 2; ++nt) {
      float v0 = a0[nt], v1 = a1[nt][0], v2 = a1[nt][1], v3 = a1[nt][2];
      v0 += __shfl_xor(v0, 16); v0 += __shfl_xor(v0, 32);
      v1 += __shfl_xor(v1, 16); v1 += __shfl_xor(v1, 32);
      v2 += __shfl_xor(v2, 16); v2 += __shfl_xor(v2, 32);
      v3 += __shfl_xor(v3, 16); v3 += __shfl_xor(v3, 32);
      if (quad == 0) {
        size_t base = (size_t)(b * NN + rglob) * HH + w * 32 + nt * 16 + nlo;
        apout[(l * 4 + 0) * PLANE + base] = bf1(v0 * invAvg);
        apout[(l * 4 + 1) * PLANE + base] = bf1(v1);
        apout[(l * 4 + 2) * PLANE + base] = bf1(v2);
        apout[(l * 4 + 3) * PLANE + base] = bf1(v3);
      }
    }
  };

#pragma unroll
  for (int pp = 0; pp < 2; ++pp) {
    int rb0 = r0 + pp * 2;

    // ---- Stage A: geometry + bessel for pair (rb0, rb0+1) ----
    {
      int s = tid & 63;
      int ksel = (tid >> 6) & 1;
      int ri = (tid >> 7) & 1;
      int r = rb0 + ri;
      const float* pb = pos + b * NN * 3;
      float dx = pb[r * 3 + 0] - pb[s * 3 + 0];
      float dy = pb[r * 3 + 1] - pb[s * 3 + 1];
      float dz = pb[r * 3 + 2] - pb[s * 3 + 2];
      float rr = sqrtf(dx * dx + dy * dy + dz * dz + 1e-12f);
      float inv = __builtin_amdgcn_rcpf(rr);
      if (ksel == 0) {
        float ia = inv * invAvg;
        sh_uf[ri][s][0] = dx * ia;
        sh_uf[ri][s][1] = dy * ia;
        sh_uf[ri][s][2] = dz * ia;
      }
      const float PI_OVER_5 = 0.628318530717958647692f;
      float fc = (s != r && rr < 5.0f) ? 0.5f * (__cosf(PI_OVER_5 * rr) + 1.0f) : 0.0f;
      float base = PI_OVER_5 * rr;
      float sc = inv * fc;
      int k0 = ksel * 4;
      float v0 = __sinf((float)(k0 + 1) * base) * sc;
      float v1 = __sinf((float)(k0 + 2) * base) * sc;
      float v2 = __sinf((float)(k0 + 3) * base) * sc;
      float v3 = __sinf((float)(k0 + 4) * base) * sc;
      *(unsigned*)&sh_rbh[ri][s][k0]     = bf2(v0, v1);
      *(unsigned*)&sh_rbh[ri][s][k0 + 2] = bf2(v2, v3);
    }
    // ---- l==1, first pair only: stage a0_l0 tile (bf16) into sh_S[0] ----
    if (pp == 0 && l) {
      for (int i = tid; i < NN * 64; i += 256) {
        int s = i >> 6, c2 = (i & 63) * 2;
        *(unsigned*)&sh_S[0][s][c2] =
            *(const unsigned*)&a0in[((size_t)b * NN + s) * HH + c2];
      }
    }
    __syncthreads();   // bar1: rbh/uf (and a0 tile) ready

    // ---- l==1, once per block: hbv += a0_l0 @ Wupd0 via MFMA ----
    if (pp == 0 && l) {
      const unsigned short* Bu = Wpack + 2 * 16384;
#pragma unroll
      for (int mt = 0; mt < 4; ++mt) {
        short8 afr[4];
#pragma unroll
        for (int kt = 0; kt < 4; ++kt)
          afr[kt] = *(const short8*)&sh_S[0][mt * 16 + nlo][kt * 32 + quad * 8];
#pragma unroll
        for (int nt = 0; nt < 2; ++nt)
#pragma unroll
          for (int kt = 0; kt < 4; ++kt) {
            short8 bfr2 = *(const short8*)&Bu[((kt * 128 + w * 32 + nt * 16 + nlo) * 4 + quad) * 8];
            hbv[mt][nt] = __builtin_amdgcn_mfma_f32_16x16x32_bf16(afr[kt], bfr2, hbv[mt][nt], 0, 0, 0);
          }
      }
      __syncthreads();   // bar2: sh_S[0] reads done before StageB overwrites
    }

    stageB(0, 0);
    __syncthreads();     // S0 ready
    stageB(1, 1);        // overlaps mainG(0) below (separate buffer, no barrier)
    mainG(0, 0, rb0 + 0);
    __syncthreads();     // S1 ready (and S0 reads done)
    mainG(1, 1, rb0 + 1);
    if (pp == 0) __syncthreads();  // rbh/uf reads done before next Stage A
  }
}

// Final update + readout, 8 rows/block (grid 512), 10 MFMA GEMMs in-block.
__global__ __launch_bounds__(256) void k_update_ro(
    const unsigned short* __restrict__ apbf, const float* __restrict__ hA,
    const unsigned short* __restrict__ Wpack,
    const float* __restrict__ fs, float* __restrict__ out) {
  __shared__ __align__(16) unsigned short sh_a[8][8][136];   // [0] aliased by q later
  __shared__ __align__(16) unsigned short sh_h[8][136];
  __shared__ float red[4][8][3];
  int tid = threadIdx.x, w = tid >> 6, lane = tid & 63;
  int nlo = lane & 15, quad = lane >> 4;
  int row0 = blockIdx.x * 8;
  for (int i = tid; i < 8 * 8 * 64; i += 256) {
    int p = i >> 9, rr = (i >> 6) & 7, c2 = (i & 63) * 2;
    *(unsigned*)&sh_a[p][rr][c2] =
        *(const unsigned*)&apbf[p * PLANE + (size_t)(row0 + rr) * HH + c2];
  }
  f32x4 Ch[2];
#pragma unroll
  for (int nt = 0; nt < 2; ++nt)
#pragma unroll
    for (int reg = 0; reg < 4; ++reg)
      Ch[nt][reg] = (quad < 2)
          ? hA[(size_t)(row0 + quad * 4 + reg) * HH + w * 32 + nt * 16 + nlo] : 0.f;
  __syncthreads();
  gemm8(sh_a[0], Wpack + 2 * 16384, w, nlo, quad, Ch);   // + a0l0@Wupd0
  gemm8(sh_a[4], Wpack + 3 * 16384, w, nlo, quad, Ch);   // + a0l1@Wupd1
  f32x4 Cx[2] = {{0,0,0,0},{0,0,0,0}};
  f32x4 Cy[2] = {{0,0,0,0},{0,0,0,0}};
  f32x4 Cz[2] = {{0,0,0,0},{0,0,0,0}};
  gemm8(sh_a[1], Wpack + 4 * 16384, w, nlo, quad, Cx);
  gemm8(sh_a[5], Wpack + 5 * 16384, w, nlo, quad, Cx);
  gemm8(sh_a[2], Wpack + 4 * 16384, w, nlo, quad, Cy);
  gemm8(sh_a[6], Wpack + 5 * 16384, w, nlo, quad, Cy);
  gemm8(sh_a[3], Wpack + 4 * 16384, w, nlo, quad, Cz);
  gemm8(sh_a[7], Wpack + 5 * 16384, w, nlo, quad, Cz);
  if (quad < 2) {
#pragma unroll
    for (int nt = 0; nt < 2; ++nt)
#pragma unroll
      for (int reg = 0; reg < 4; ++reg)
        sh_h[quad * 4 + reg][w * 32 + nt * 16 + nlo] = bf1(Ch[nt][reg]);
  }
  __syncthreads();   // sh_h ready; sh_a reads done -> sh_a[0] free to alias
  unsigned short (*sh_q)[136] = sh_a[0];
  f32x4 Cq[2] = {{0,0,0,0},{0,0,0,0}};
  gemm8(sh_h, Wpack + 6 * 16384, w, nlo, quad, Cq);
  if (quad < 2) {
#pragma unroll
    for (int nt = 0; nt < 2; ++nt)
#pragma unroll
      for (int reg = 0; reg < 4; ++reg)
        sh_q[quad * 4 + reg][w * 32 + nt * 16 + nlo] = bf1(silu_f(Cq[nt][reg]));
  }
  __syncthreads();
  f32x4 Cg[2] = {{0,0,0,0},{0,0,0,0}};
  gemm8(sh_q, Wpack + 7 * 16384, w, nlo, quad, Cg);
  float pr[3][4];
#pragma unroll
  for (int d = 0; d < 3; ++d)
#pragma unroll
    for (int reg = 0; reg < 4; ++reg) pr[d][reg] = 0.f;
#pragma unroll
  for (int nt = 0; nt < 2; ++nt)
#pragma unroll
    for (int reg = 0; reg < 4; ++reg) {
      float gv = Cg[nt][reg];
      pr[0][reg] += gv * Cx[nt][reg];
      pr[1][reg] += gv * Cy[nt][reg];
      pr[2][reg] += gv * Cz[nt][reg];
    }
#pragma unroll
  for (int off = 1; off < 16; off <<= 1)
#pragma unroll
    for (int d = 0; d < 3; ++d)
#pragma unroll
      for (int reg = 0; reg < 4; ++reg)
        pr[d][reg] += __shfl_xor(pr[d][reg], off);
  if (nlo == 0 && quad < 2) {
#pragma unroll
    for (int d = 0; d < 3; ++d)
#pragma unroll
      for (int reg = 0; reg < 4; ++reg)
        red[w][quad * 4 + reg][d] = pr[d][reg];
  }
  __syncthreads();
  if (tid < 24) {
    int row = tid / 3, d = tid % 3;
    float s = red[0][row][d] + red[1][row][d] + red[2][row][d] + red[3][row][d];
    out[(size_t)(row0 + row) * 3 + d] = s * fs[0];
  }
}

extern "C" void kernel_launch(void* const* d_in, const int* in_sizes, int n_in,
                              void* d_out, int out_size, void* d_ws, size_t ws_size,
                              hipStream_t stream) {
  const float* pos  = (const float*)d_in[0];
  const int*   z    = (const int*)d_in[1];
  const float* gf   = (const float*)d_in[2];
  const float* emb  = (const float*)d_in[3];
  const float* Wt   = (const float*)d_in[4];
  const float* Wr1  = (const float*)d_in[5];
  const float* Wr2  = (const float*)d_in[6];
  const float* Wupd = (const float*)d_in[7];
  const float* Wmix = (const float*)d_in[8];
  const float* Wg1  = (const float*)d_in[9];
  const float* Wg2  = (const float*)d_in[10];
  const float* fs   = (const float*)d_in[11];
  float* out = (float*)d_out;

  float* ws = (float*)d_ws;
  float* hA = ws;                                         // 2 MB
  unsigned short* apbf = (unsigned short*)(ws + PLANE);   // 8 bf16 planes = 8 MB
  unsigned short* Wpack = (unsigned short*)(ws + 5 * PLANE);  // 272 KB

  k_init<<<dim3(256), dim3(256), 0, stream>>>(emb, z, gf, Wt, Wr1, Wr2, Wupd,
                                              Wmix, Wg1, Wg2, hA, Wpack);
  k_layer<<<dim3(BB * 16), dim3(256), 0, stream>>>(pos, hA, apbf, apbf, Wpack, 0);
  k_layer<<<dim3(BB * 16), dim3(256), 0, stream>>>(pos, hA, apbf, apbf, Wpack, 1);
  k_update_ro<<<dim3(512), dim3(256), 0, stream>>>(apbf, hA, Wpack, fs, out);
}

// Round 5
// 154.593 us; speedup vs baseline: 1.4396x; 1.4396x over previous
//
#include <hip/hip_runtime.h>
#include <math.h>

#define NN 64      // nodes per graph
#define HH 128     // hidden channels
#define NBB 8      // bessel basis
#define TT 32      // time embedding dim
#define BB 64      // batch
#define NROW (BB * NN)        // 4096 total rows
#define PLANE ((size_t)NROW * HH)   // 524288
#define WR1OFF (8 * 16384)    // Wr1 B-frag slabs in Wpack (2 x 4096)

typedef __attribute__((ext_vector_type(8))) short short8;
typedef __attribute__((ext_vector_type(4))) float f32x4;
typedef __attribute__((ext_vector_type(2))) float f32x2;
typedef __attribute__((ext_vector_type(2))) unsigned int u32x2;

__device__ __forceinline__ float silu_f(float x) {
  return x * __builtin_amdgcn_rcpf(1.0f + __expf(-x));
}

__device__ __forceinline__ unsigned short bf1(float x) {
  __bf16 h = (__bf16)x;
  return *(unsigned short*)&h;
}
__device__ __forceinline__ unsigned bf2(float lo, float hi) {
  return (unsigned)bf1(lo) | ((unsigned)bf1(hi) << 16);
}

// 8-row MFMA GEMM tile: A rows 8..15 zero. C map: row=quad*4+reg (<8), col=w*32+nt*16+nlo.
__device__ __forceinline__ void gemm8(
    const unsigned short (*sA)[136], const unsigned short* __restrict__ Bp,
    int w, int nlo, int quad, f32x4 C[2]) {
  const short8 z8 = {0, 0, 0, 0, 0, 0, 0, 0};
  short8 afr[4];
#pragma unroll
  for (int kt = 0; kt < 4; ++kt)
    afr[kt] = (nlo < 8) ? *(const short8*)&sA[nlo][kt * 32 + quad * 8] : z8;
#pragma unroll
  for (int nt = 0; nt < 2; ++nt)
#pragma unroll
    for (int kt = 0; kt < 4; ++kt) {
      short8 bfr = *(const short8*)&Bp[((kt * 128 + w * 32 + nt * 16 + nlo) * 4 + quad) * 8];
      C[nt] = __builtin_amdgcn_mfma_f32_16x16x32_bf16(afr[kt], bfr, C[nt], 0, 0, 0);
    }
}

// Grid 256. Pack all weights -> bf16 MFMA-B-frag order (coalesced writes, gathered
// reads); blocks<64 also init h.
__global__ __launch_bounds__(256) void k_init(
    const float* __restrict__ emb, const int* __restrict__ z,
    const float* __restrict__ gf, const float* __restrict__ Wt,
    const float* __restrict__ Wr1, const float* __restrict__ Wr2,
    const float* __restrict__ Wupd, const float* __restrict__ Wmix,
    const float* __restrict__ Wg1, const float* __restrict__ Wg2,
    float* __restrict__ h, unsigned short* __restrict__ Wpack) {
  __shared__ float tvec[HH];
  __shared__ int sz[NN];
  int b4 = blockIdx.x, tid = threadIdx.x;
  {
    // thread <-> output dword: p2 in [0,65536); p = output ushort index (even)
    int p2 = b4 * 256 + tid;
    int p = p2 * 2;
    int m = p >> 14;                 // matrix 0..7
    int j = p & 7;                   // 0,2,4,6 (handles j and j+1)
    int q = (p >> 3) & 3;
    int n = (p >> 5) & 127;
    int kt = (p >> 12) & 3;
    int k = kt * 32 + q * 8 + j;     // source row; pair (k, k+1)
    const float* src;
    int base;
    if (m < 2) { src = Wr2; base = m * 16384; }
    else if (m < 4) { src = Wupd; base = (m - 2) * 16384; }
    else if (m < 6) { src = Wmix; base = (m - 4) * 16384; }
    else if (m == 6) { src = Wg1; base = 0; }
    else { src = Wg2; base = 0; }
    float v0 = src[base + k * 128 + n];
    float v1 = src[base + (k + 1) * 128 + n];
    *(unsigned*)&Wpack[p] = bf2(v0, v1);
  }
  if (tid < 32) {                           // Wr1 zero-padded B-frags
    int e = b4 * 32 + tid;                  // 0..8191
    int l = e >> 12, p = e & 4095;          // p = (n*4+q)*8+j
    int n = p >> 5, q = (p >> 3) & 3, j = p & 7;
    float val = (q == 0) ? Wr1[l * NBB * HH + j * HH + n] : 0.f;
    Wpack[WR1OFF + l * 4096 + p] = bf1(val);
  }
  if (b4 < 64) {
    int b = b4;
    if (tid < NN) sz[tid] = z[b * NN + tid];
    if (tid < HH) {
      float acc = 0.f;
#pragma unroll
      for (int k = 0; k < TT; ++k) acc += gf[b * TT + k] * Wt[k * HH + tid];
      tvec[tid] = acc;
    }
    __syncthreads();
    for (int i = tid; i < NN * HH; i += 256) {
      int n = i >> 7, c = i & 127;
      h[(size_t)b * NN * HH + i] = emb[sz[n] * HH + c] + tvec[c];
    }
  }
}

// One block (256 thr = 4 waves) per (b, receiver-quad {4rp..4rp+3}), as two pairs.
// sh_S double-buffered: StageB(ri+1) overlaps main-GEMM(ri). Epilogue a0/a1 via
// in-register shuffle reduction (no M0T tile, no U-GEMM). LDS 38912 B.
// NOTE: no min-waves pin -- __launch_bounds__(256,4) forced VGPR=64 and ~200 MB/dispatch
// of scratch-spill traffic (R4 counters: FETCH 120 MB, WRITE 94 MB vs ~10 MB useful).
__global__ __launch_bounds__(256) void k_layer(
    const float* __restrict__ pos,
    const float* __restrict__ hA,
    const unsigned short* __restrict__ a0in,   // bf16 plane 0 (l=1 only)
    unsigned short* __restrict__ apout,        // bf16 planes
    const unsigned short* __restrict__ Wpack,
    int l) {
  __shared__ __align__(16) unsigned short sh_S[2][NN][136];  // 34816 B (buf0 = a0 tile)
  __shared__ __align__(16) unsigned short sh_rbh[2][NN][8];  // 2048 B
  __shared__ __align__(16) float sh_uf[2][NN][4];            // 2048 B: u/63 (f32)

  int blk = blockIdx.x;          // b*16 + rp4
  int b = blk >> 4, rp4 = blk & 15;
  int r0 = rp4 * 4;
  int tid = threadIdx.x;
  int w = tid >> 6, lane = tid & 63;
  int nlo = lane & 15, quad = lane >> 4;
  const float invAvg = 1.0f / 63.0f;

  // ---- hbv base prefetch from hA (C-reg layout) ----
  f32x4 hbv[4][2];
#pragma unroll
  for (int mt = 0; mt < 4; ++mt)
#pragma unroll
    for (int nt = 0; nt < 2; ++nt)
#pragma unroll
      for (int reg = 0; reg < 4; ++reg)
        hbv[mt][nt][reg] =
            hA[((size_t)b * NN + mt * 16 + quad * 4 + reg) * HH + w * 32 + nt * 16 + nlo];

  // ---- hoisted fragment loads (L2-hot, shared by all 4 receivers) ----
  const unsigned short* Wr1p = Wpack + WR1OFF + l * 4096;
  short8 bw[2];
#pragma unroll
  for (int nt = 0; nt < 2; ++nt)
    bw[nt] = *(const short8*)&Wr1p[((w * 32 + nt * 16 + nlo) * 4 + quad) * 8];
  const unsigned short* Bbase = Wpack + l * 16384;
  short8 bfr[4][2];
#pragma unroll
  for (int kt = 0; kt < 4; ++kt)
#pragma unroll
    for (int nt = 0; nt < 2; ++nt)
      bfr[kt][nt] = *(const short8*)&Bbase[((kt * 128 + w * 32 + nt * 16 + nlo) * 4 + quad) * 8];

  const short8 zero8 = {0, 0, 0, 0, 0, 0, 0, 0};

  // StageB: S_ri = silu(rb_ri @ Wr1) -> sh_S[buf]
  auto stageB = [&](int ri, int buf) {
#pragma unroll
    for (int mtp = 0; mtp < 2; ++mtp) {
      f32x4 Cs[2][2];
#pragma unroll
      for (int mi = 0; mi < 2; ++mi)
#pragma unroll
        for (int nt = 0; nt < 2; ++nt) Cs[mi][nt] = (f32x4){0.f, 0.f, 0.f, 0.f};
#pragma unroll
      for (int mi = 0; mi < 2; ++mi) {
        int mt = mtp * 2 + mi;
        short8 afr = (quad == 0) ? *(const short8*)&sh_rbh[ri][mt * 16 + nlo][0] : zero8;
#pragma unroll
        for (int nt = 0; nt < 2; ++nt)
          Cs[mi][nt] = __builtin_amdgcn_mfma_f32_16x16x32_bf16(afr, bw[nt], Cs[mi][nt], 0, 0, 0);
      }
#pragma unroll
      for (int mi = 0; mi < 2; ++mi)
#pragma unroll
        for (int nt = 0; nt < 2; ++nt)
#pragma unroll
          for (int reg = 0; reg < 4; ++reg) {
            int s = (mtp * 2 + mi) * 16 + quad * 4 + reg;
            int c = w * 32 + nt * 16 + nlo;
            sh_S[buf][s][c] = bf1(silu_f(Cs[mi][nt][reg]));
          }
    }
  };

  // Main GEMM + in-register a0/a1 reduction for receiver rb0+ri reading sh_S[buf].
  auto mainG = [&](int ri, int buf, int rglob) {
    float a0[2] = {0.f, 0.f};
    float a1[2][3] = {{0.f, 0.f, 0.f}, {0.f, 0.f, 0.f}};
#pragma unroll
    for (int mt = 0; mt < 4; ++mt) {
      short8 afr[4];
      int s_a = mt * 16 + nlo;
#pragma unroll
      for (int kt = 0; kt < 4; ++kt)
        afr[kt] = *(const short8*)&sh_S[buf][s_a][kt * 32 + quad * 8];
      f32x4 u3[4];
#pragma unroll
      for (int reg = 0; reg < 4; ++reg)
        u3[reg] = *(const f32x4*)&sh_uf[ri][mt * 16 + quad * 4 + reg][0];
#pragma unroll
      for (int nt = 0; nt < 2; ++nt) {
        f32x4 C = {0.f, 0.f, 0.f, 0.f};
#pragma unroll
        for (int kt = 0; kt < 4; ++kt)
          C = __builtin_amdgcn_mfma_f32_16x16x32_bf16(afr[kt], bfr[kt][nt], C, 0, 0, 0);
#pragma unroll
        for (int reg = 0; reg < 4; ++reg) {
          float m0 = C[reg] * hbv[mt][nt][reg];
          a0[nt] += m0;
          a1[nt][0] += u3[reg][0] * m0;
          a1[nt][1] += u3[reg][1] * m0;
          a1[nt][2] += u3[reg][2] * m0;
        }
      }
    }
    // reduce over quads (rows) and store; cols = w*32+nt*16+nlo
#pragma unroll
    for (int nt = 0; nt < 2; ++nt) {
      float v0 = a0[nt], v1 = a1[nt][0], v2 = a1[nt][1], v3 = a1[nt][2];
      v0 += __shfl_xor(v0, 16); v0 += __shfl_xor(v0, 32);
      v1 += __shfl_xor(v1, 16); v1 += __shfl_xor(v1, 32);
      v2 += __shfl_xor(v2, 16); v2 += __shfl_xor(v2, 32);
      v3 += __shfl_xor(v3, 16); v3 += __shfl_xor(v3, 32);
      if (quad == 0) {
        size_t base = (size_t)(b * NN + rglob) * HH + w * 32 + nt * 16 + nlo;
        apout[(l * 4 + 0) * PLANE + base] = bf1(v0 * invAvg);
        apout[(l * 4 + 1) * PLANE + base] = bf1(v1);
        apout[(l * 4 + 2) * PLANE + base] = bf1(v2);
        apout[(l * 4 + 3) * PLANE + base] = bf1(v3);
      }
    }
  };

#pragma unroll
  for (int pp = 0; pp < 2; ++pp) {
    int rb0 = r0 + pp * 2;

    // ---- Stage A: geometry + bessel for pair (rb0, rb0+1) ----
    {
      int s = tid & 63;
      int ksel = (tid >> 6) & 1;
      int ri = (tid >> 7) & 1;
      int r = rb0 + ri;
      const float* pb = pos + b * NN * 3;
      float dx = pb[r * 3 + 0] - pb[s * 3 + 0];
      float dy = pb[r * 3 + 1] - pb[s * 3 + 1];
      float dz = pb[r * 3 + 2] - pb[s * 3 + 2];
      float rr = sqrtf(dx * dx + dy * dy + dz * dz + 1e-12f);
      float inv = __builtin_amdgcn_rcpf(rr);
      if (ksel == 0) {
        float ia = inv * invAvg;
        sh_uf[ri][s][0] = dx * ia;
        sh_uf[ri][s][1] = dy * ia;
        sh_uf[ri][s][2] = dz * ia;
      }
      const float PI_OVER_5 = 0.628318530717958647692f;
      float fc = (s != r && rr < 5.0f) ? 0.5f * (__cosf(PI_OVER_5 * rr) + 1.0f) : 0.0f;
      float base = PI_OVER_5 * rr;
      float sc = inv * fc;
      int k0 = ksel * 4;
      float v0 = __sinf((float)(k0 + 1) * base) * sc;
      float v1 = __sinf((float)(k0 + 2) * base) * sc;
      float v2 = __sinf((float)(k0 + 3) * base) * sc;
      float v3 = __sinf((float)(k0 + 4) * base) * sc;
      *(unsigned*)&sh_rbh[ri][s][k0]     = bf2(v0, v1);
      *(unsigned*)&sh_rbh[ri][s][k0 + 2] = bf2(v2, v3);
    }
    // ---- l==1, first pair only: stage a0_l0 tile (bf16) into sh_S[0] ----
    if (pp == 0 && l) {
      for (int i = tid; i < NN * 64; i += 256) {
        int s = i >> 6, c2 = (i & 63) * 2;
        *(unsigned*)&sh_S[0][s][c2] =
            *(const unsigned*)&a0in[((size_t)b * NN + s) * HH + c2];
      }
    }
    __syncthreads();   // bar1: rbh/uf (and a0 tile) ready

    // ---- l==1, once per block: hbv += a0_l0 @ Wupd0 via MFMA ----
    if (pp == 0 && l) {
      const unsigned short* Bu = Wpack + 2 * 16384;
#pragma unroll
      for (int mt = 0; mt < 4; ++mt) {
        short8 afr[4];
#pragma unroll
        for (int kt = 0; kt < 4; ++kt)
          afr[kt] = *(const short8*)&sh_S[0][mt * 16 + nlo][kt * 32 + quad * 8];
#pragma unroll
        for (int nt = 0; nt < 2; ++nt)
#pragma unroll
          for (int kt = 0; kt < 4; ++kt) {
            short8 bfr2 = *(const short8*)&Bu[((kt * 128 + w * 32 + nt * 16 + nlo) * 4 + quad) * 8];
            hbv[mt][nt] = __builtin_amdgcn_mfma_f32_16x16x32_bf16(afr[kt], bfr2, hbv[mt][nt], 0, 0, 0);
          }
      }
      __syncthreads();   // bar2: sh_S[0] reads done before StageB overwrites
    }

    stageB(0, 0);
    __syncthreads();     // S0 ready
    stageB(1, 1);        // overlaps mainG(0) below (separate buffer, no barrier)
    mainG(0, 0, rb0 + 0);
    __syncthreads();     // S1 ready (and S0 reads done)
    mainG(1, 1, rb0 + 1);
    if (pp == 0) __syncthreads();  // rbh/uf reads done before next Stage A
  }
}

// Final update + readout, 8 rows/block (grid 512), 10 MFMA GEMMs in-block.
__global__ __launch_bounds__(256) void k_update_ro(
    const unsigned short* __restrict__ apbf, const float* __restrict__ hA,
    const unsigned short* __restrict__ Wpack,
    const float* __restrict__ fs, float* __restrict__ out) {
  __shared__ __align__(16) unsigned short sh_a[8][8][136];   // [0] aliased by q later
  __shared__ __align__(16) unsigned short sh_h[8][136];
  __shared__ float red[4][8][3];
  int tid = threadIdx.x, w = tid >> 6, lane = tid & 63;
  int nlo = lane & 15, quad = lane >> 4;
  int row0 = blockIdx.x * 8;
  for (int i = tid; i < 8 * 8 * 64; i += 256) {
    int p = i >> 9, rr = (i >> 6) & 7, c2 = (i & 63) * 2;
    *(unsigned*)&sh_a[p][rr][c2] =
        *(const unsigned*)&apbf[p * PLANE + (size_t)(row0 + rr) * HH + c2];
  }
  f32x4 Ch[2];
#pragma unroll
  for (int nt = 0; nt < 2; ++nt)
#pragma unroll
    for (int reg = 0; reg < 4; ++reg)
      Ch[nt][reg] = (quad < 2)
          ? hA[(size_t)(row0 + quad * 4 + reg) * HH + w * 32 + nt * 16 + nlo] : 0.f;
  __syncthreads();
  gemm8(sh_a[0], Wpack + 2 * 16384, w, nlo, quad, Ch);   // + a0l0@Wupd0
  gemm8(sh_a[4], Wpack + 3 * 16384, w, nlo, quad, Ch);   // + a0l1@Wupd1
  f32x4 Cx[2] = {{0,0,0,0},{0,0,0,0}};
  f32x4 Cy[2] = {{0,0,0,0},{0,0,0,0}};
  f32x4 Cz[2] = {{0,0,0,0},{0,0,0,0}};
  gemm8(sh_a[1], Wpack + 4 * 16384, w, nlo, quad, Cx);
  gemm8(sh_a[5], Wpack + 5 * 16384, w, nlo, quad, Cx);
  gemm8(sh_a[2], Wpack + 4 * 16384, w, nlo, quad, Cy);
  gemm8(sh_a[6], Wpack + 5 * 16384, w, nlo, quad, Cy);
  gemm8(sh_a[3], Wpack + 4 * 16384, w, nlo, quad, Cz);
  gemm8(sh_a[7], Wpack + 5 * 16384, w, nlo, quad, Cz);
  if (quad < 2) {
#pragma unroll
    for (int nt = 0; nt < 2; ++nt)
#pragma unroll
      for (int reg = 0; reg < 4; ++reg)
        sh_h[quad * 4 + reg][w * 32 + nt * 16 + nlo] = bf1(Ch[nt][reg]);
  }
  __syncthreads();   // sh_h ready; sh_a reads done -> sh_a[0] free to alias
  unsigned short (*sh_q)[136] = sh_a[0];
  f32x4 Cq[2] = {{0,0,0,0},{0,0,0,0}};
  gemm8(sh_h, Wpack + 6 * 16384, w, nlo, quad, Cq);
  if (quad < 2) {
#pragma unroll
    for (int nt = 0; nt < 2; ++nt)
#pragma unroll
      for (int reg = 0; reg < 4; ++reg)
        sh_q[quad * 4 + reg][w * 32 + nt * 16 + nlo] = bf1(silu_f(Cq[nt][reg]));
  }
  __syncthreads();
  f32x4 Cg[2] = {{0,0,0,0},{0,0,0,0}};
  gemm8(sh_q, Wpack + 7 * 16384, w, nlo, quad, Cg);
  float pr[3][4];
#pragma unroll
  for (int d = 0; d < 3; ++d)
#pragma unroll
    for (int reg = 0; reg < 4; ++reg) pr[d][reg] = 0.f;
#pragma unroll
  for (int nt = 0; nt < 2; ++nt)
#pragma unroll
    for (int reg = 0; reg < 4; ++reg) {
      float gv = Cg[nt][reg];
      pr[0][reg] += gv * Cx[nt][reg];
      pr[1][reg] += gv * Cy[nt][reg];
      pr[2][reg] += gv * Cz[nt][reg];
    }
#pragma unroll
  for (int off = 1; off < 16; off <<= 1)
#pragma unroll
    for (int d = 0; d < 3; ++d)
#pragma unroll
      for (int reg = 0; reg < 4; ++reg)
        pr[d][reg] += __shfl_xor(pr[d][reg], off);
  if (nlo == 0 && quad < 2) {
#pragma unroll
    for (int d = 0; d < 3; ++d)
#pragma unroll
      for (int reg = 0; reg < 4; ++reg)
        red[w][quad * 4 + reg][d] = pr[d][reg];
  }
  __syncthreads();
  if (tid < 24) {
    int row = tid / 3, d = tid % 3;
    float s = red[0][row][d] + red[1][row][d] + red[2][row][d] + red[3][row][d];
    out[(size_t)(row0 + row) * 3 + d] = s * fs[0];
  }
}

extern "C" void kernel_launch(void* const* d_in, const int* in_sizes, int n_in,
                              void* d_out, int out_size, void* d_ws, size_t ws_size,
                              hipStream_t stream) {
  const float* pos  = (const float*)d_in[0];
  const int*   z    = (const int*)d_in[1];
  const float* gf   = (const float*)d_in[2];
  const float* emb  = (const float*)d_in[3];
  const float* Wt   = (const float*)d_in[4];
  const float* Wr1  = (const float*)d_in[5];
  const float* Wr2  = (const float*)d_in[6];
  const float* Wupd = (const float*)d_in[7];
  const float* Wmix = (const float*)d_in[8];
  const float* Wg1  = (const float*)d_in[9];
  const float* Wg2  = (const float*)d_in[10];
  const float* fs   = (const float*)d_in[11];
  float* out = (float*)d_out;

  float* ws = (float*)d_ws;
  float* hA = ws;                                         // 2 MB
  unsigned short* apbf = (unsigned short*)(ws + PLANE);   // 8 bf16 planes = 8 MB
  unsigned short* Wpack = (unsigned short*)(ws + 5 * PLANE);  // 272 KB

  k_init<<<dim3(256), dim3(256), 0, stream>>>(emb, z, gf, Wt, Wr1, Wr2, Wupd,
                                              Wmix, Wg1, Wg2, hA, Wpack);
  k_layer<<<dim3(BB * 16), dim3(256), 0, stream>>>(pos, hA, apbf, apbf, Wpack, 0);
  k_layer<<<dim3(BB * 16), dim3(256), 0, stream>>>(pos, hA, apbf, apbf, Wpack, 1);
  k_update_ro<<<dim3(512), dim3(256), 0, stream>>>(apbf, hA, Wpack, fs, out);
}

// Round 6
// 151.491 us; speedup vs baseline: 1.4691x; 1.0205x over previous
//
#include <hip/hip_runtime.h>
#include <math.h>

#define NN 64      // nodes per graph
#define HH 128     // hidden channels
#define NBB 8      // bessel basis
#define TT 32      // time embedding dim
#define BB 64      // batch
#define NROW (BB * NN)        // 4096 total rows
#define PLANE ((size_t)NROW * HH)   // 524288
#define WR1OFF (8 * 16384)    // Wr1 B-frag slabs in Wpack (2 x 4096)

// XOR column swizzle (T2): row-major [R][136] bf16 tiles read column-sliced by
// b128 have stride 68 words = 4 mod 32 banks (8-way). XOR bits 4-6 of the col
// index with row&7: bijective, preserves 16B alignment, spreads to ~2-way.
#define SWZ(s, c) ((c) ^ (((s) & 7) << 4))

typedef __attribute__((ext_vector_type(8))) short short8;
typedef __attribute__((ext_vector_type(8))) unsigned short ushort8;
typedef __attribute__((ext_vector_type(4))) float f32x4;
typedef __attribute__((ext_vector_type(2))) float f32x2;
typedef __attribute__((ext_vector_type(2))) unsigned int u32x2;

__device__ __forceinline__ float silu_f(float x) {
  return x * __builtin_amdgcn_rcpf(1.0f + __expf(-x));
}

__device__ __forceinline__ unsigned short bf1(float x) {
  __bf16 h = (__bf16)x;
  return *(unsigned short*)&h;
}
__device__ __forceinline__ unsigned bf2(float lo, float hi) {
  return (unsigned)bf1(lo) | ((unsigned)bf1(hi) << 16);
}

// 8-row MFMA GEMM tile: A rows 8..15 zero. C map: row=quad*4+reg (<8), col=w*32+nt*16+nlo.
// A tile is column-SWIZZLED (writers must use SWZ too).
__device__ __forceinline__ void gemm8(
    const unsigned short (*sA)[136], const unsigned short* __restrict__ Bp,
    int w, int nlo, int quad, f32x4 C[2]) {
  const short8 z8 = {0, 0, 0, 0, 0, 0, 0, 0};
  short8 afr[4];
#pragma unroll
  for (int kt = 0; kt < 4; ++kt)
    afr[kt] = (nlo < 8) ? *(const short8*)&sA[nlo][SWZ(nlo, kt * 32 + quad * 8)] : z8;
#pragma unroll
  for (int nt = 0; nt < 2; ++nt)
#pragma unroll
    for (int kt = 0; kt < 4; ++kt) {
      short8 bfr = *(const short8*)&Bp[((kt * 128 + w * 32 + nt * 16 + nlo) * 4 + quad) * 8];
      C[nt] = __builtin_amdgcn_mfma_f32_16x16x32_bf16(afr[kt], bfr, C[nt], 0, 0, 0);
    }
}

// Grid 256. Pack all weights -> bf16 MFMA-B-frag order (coalesced writes, gathered
// reads); h init spread across ALL 256 blocks (4 blocks per graph, 16 rows each).
__global__ __launch_bounds__(256) void k_init(
    const float* __restrict__ emb, const int* __restrict__ z,
    const float* __restrict__ gf, const float* __restrict__ Wt,
    const float* __restrict__ Wr1, const float* __restrict__ Wr2,
    const float* __restrict__ Wupd, const float* __restrict__ Wmix,
    const float* __restrict__ Wg1, const float* __restrict__ Wg2,
    float* __restrict__ h, unsigned short* __restrict__ Wpack) {
  __shared__ float tvec[HH];
  __shared__ int sz[16];
  int b4 = blockIdx.x, tid = threadIdx.x;
  {
    // thread <-> output dword: p2 in [0,65536); p = output ushort index (even)
    int p2 = b4 * 256 + tid;
    int p = p2 * 2;
    int m = p >> 14;                 // matrix 0..7
    int j = p & 7;                   // 0,2,4,6 (handles j and j+1)
    int q = (p >> 3) & 3;
    int n = (p >> 5) & 127;
    int kt = (p >> 12) & 3;
    int k = kt * 32 + q * 8 + j;     // source row; pair (k, k+1)
    const float* src;
    int base;
    if (m < 2) { src = Wr2; base = m * 16384; }
    else if (m < 4) { src = Wupd; base = (m - 2) * 16384; }
    else if (m < 6) { src = Wmix; base = (m - 4) * 16384; }
    else if (m == 6) { src = Wg1; base = 0; }
    else { src = Wg2; base = 0; }
    float v0 = src[base + k * 128 + n];
    float v1 = src[base + (k + 1) * 128 + n];
    *(unsigned*)&Wpack[p] = bf2(v0, v1);
  }
  if (tid < 32) {                           // Wr1 zero-padded B-frags
    int e = b4 * 32 + tid;                  // 0..8191
    int l = e >> 12, p = e & 4095;          // p = (n*4+q)*8+j
    int n = p >> 5, q = (p >> 3) & 3, j = p & 7;
    float val = (q == 0) ? Wr1[l * NBB * HH + j * HH + n] : 0.f;
    Wpack[WR1OFF + l * 4096 + p] = bf1(val);
  }
  {
    int b = b4 >> 2;               // graph
    int n0 = (b4 & 3) * 16;        // this block's 16 rows
    if (tid < 16) sz[tid] = z[b * NN + n0 + tid];
    if (tid < HH) {
      float acc = 0.f;
#pragma unroll
      for (int k = 0; k < TT; ++k) acc += gf[b * TT + k] * Wt[k * HH + tid];
      tvec[tid] = acc;
    }
    __syncthreads();
    for (int i = tid; i < 16 * HH; i += 256) {
      int n = i >> 7, c = i & 127;
      h[(size_t)b * NN * HH + (n0 + n) * HH + c] = emb[sz[n] * HH + c] + tvec[c];
    }
  }
}

// One block (256 thr = 4 waves) per (b, receiver-quad {4rp..4rp+3}), processed as
// two pairs (R2 structure = measured best). sh_S column-swizzled (SWZ) to kill the
// 8-way bank aliasing on b128 A-frag reads (R3: 2.26M conflict cycles/dispatch).
__global__ __launch_bounds__(256) void k_layer(
    const float* __restrict__ pos,
    const float* __restrict__ hA,
    const unsigned short* __restrict__ a0in,   // bf16 plane 0 (l=1 only)
    unsigned short* __restrict__ apout,        // bf16 planes
    const unsigned short* __restrict__ Wpack,
    int l) {
  __shared__ __align__(16) unsigned short sh_S[NN][136];     // 17408 B (also a0 tile)
  __shared__ __align__(16) unsigned short sh_M0T[4][32][72]; // 18432 B, per-wave [c][s]
  __shared__ __align__(16) unsigned short sh_rbh[2][NN][8];  // 2048 B
  __shared__ __align__(16) unsigned short sh_ub[2][4][NN];   // 1024 B: U rows (bf16)

  int blk = blockIdx.x;          // b*16 + rp4
  int b = blk >> 4, rp4 = blk & 15;
  int r0 = rp4 * 4;
  int tid = threadIdx.x;
  int w = tid >> 6, lane = tid & 63;
  int nlo = lane & 15, quad = lane >> 4;

  // ---- hbv base prefetch from hA (C-reg layout) ----
  f32x4 hbv[4][2];
#pragma unroll
  for (int mt = 0; mt < 4; ++mt)
#pragma unroll
    for (int nt = 0; nt < 2; ++nt)
#pragma unroll
      for (int reg = 0; reg < 4; ++reg)
        hbv[mt][nt][reg] =
            hA[((size_t)b * NN + mt * 16 + quad * 4 + reg) * HH + w * 32 + nt * 16 + nlo];

  // ---- hoisted fragment loads (L2-hot, shared by all 4 receivers) ----
  const unsigned short* Wr1p = Wpack + WR1OFF + l * 4096;
  short8 bw[2];
#pragma unroll
  for (int nt = 0; nt < 2; ++nt)
    bw[nt] = *(const short8*)&Wr1p[((w * 32 + nt * 16 + nlo) * 4 + quad) * 8];
  const unsigned short* Bbase = Wpack + l * 16384;
  short8 bfr[4][2];
#pragma unroll
  for (int kt = 0; kt < 4; ++kt)
#pragma unroll
    for (int nt = 0; nt < 2; ++nt)
      bfr[kt][nt] = *(const short8*)&Bbase[((kt * 128 + w * 32 + nt * 16 + nlo) * 4 + quad) * 8];

  const short8 zero8 = {0, 0, 0, 0, 0, 0, 0, 0};

#pragma unroll
  for (int pp = 0; pp < 2; ++pp) {
    int rb0 = r0 + pp * 2;

    // ---- Stage A: geometry + bessel for pair (rb0, rb0+1) ----
    {
      int s = tid & 63;
      int ksel = (tid >> 6) & 1;
      int ri = (tid >> 7) & 1;
      int r = rb0 + ri;
      const float* pb = pos + b * NN * 3;
      float dx = pb[r * 3 + 0] - pb[s * 3 + 0];
      float dy = pb[r * 3 + 1] - pb[s * 3 + 1];
      float dz = pb[r * 3 + 2] - pb[s * 3 + 2];
      float rr = sqrtf(dx * dx + dy * dy + dz * dz + 1e-12f);
      float inv = __builtin_amdgcn_rcpf(rr);
      const float invAvg = 1.0f / 63.0f;
      if (ksel == 0) {
        float ia = inv * invAvg;
        sh_ub[ri][1][s] = bf1(dx * ia);
        sh_ub[ri][2][s] = bf1(dy * ia);
        sh_ub[ri][3][s] = bf1(dz * ia);
      } else {
        sh_ub[ri][0][s] = bf1(invAvg);
      }
      const float PI_OVER_5 = 0.628318530717958647692f;
      float fc = (s != r && rr < 5.0f) ? 0.5f * (__cosf(PI_OVER_5 * rr) + 1.0f) : 0.0f;
      float base = PI_OVER_5 * rr;
      float sc = inv * fc;
      int k0 = ksel * 4;
      float v0 = __sinf((float)(k0 + 1) * base) * sc;
      float v1 = __sinf((float)(k0 + 2) * base) * sc;
      float v2 = __sinf((float)(k0 + 3) * base) * sc;
      float v3 = __sinf((float)(k0 + 4) * base) * sc;
      *(unsigned*)&sh_rbh[ri][s][k0]     = bf2(v0, v1);
      *(unsigned*)&sh_rbh[ri][s][k0 + 2] = bf2(v2, v3);
    }
    // ---- l==1: stage a0_l0 tile (bf16, swizzled) into sh_S ----
    if (pp == 0 && l) {
      for (int i = tid; i < NN * 64; i += 256) {
        int s = i >> 6, c2 = (i & 63) * 2;
        *(unsigned*)&sh_S[s][SWZ(s, c2)] =
            *(const unsigned*)&a0in[((size_t)b * NN + s) * HH + c2];
      }
    }
    __syncthreads();   // bar1: rbh/ub (and a0 tile) ready

    // ---- l==1, once per block: hbv += a0_l0 @ Wupd0 via MFMA ----
    if (pp == 0 && l) {
      const unsigned short* Bu = Wpack + 2 * 16384;
#pragma unroll
      for (int mt = 0; mt < 4; ++mt) {
        short8 afr[4];
        int s_a = mt * 16 + nlo;
#pragma unroll
        for (int kt = 0; kt < 4; ++kt)
          afr[kt] = *(const short8*)&sh_S[s_a][SWZ(s_a, kt * 32 + quad * 8)];
#pragma unroll
        for (int nt = 0; nt < 2; ++nt)
#pragma unroll
          for (int kt = 0; kt < 4; ++kt) {
            short8 bfr2 = *(const short8*)&Bu[((kt * 128 + w * 32 + nt * 16 + nlo) * 4 + quad) * 8];
            hbv[mt][nt] = __builtin_amdgcn_mfma_f32_16x16x32_bf16(afr[kt], bfr2, hbv[mt][nt], 0, 0, 0);
          }
      }
      __syncthreads();   // bar2: sh_S reads done before Stage B overwrites
    }

    // U-GEMM A-frags for this pair (bf16 u rows; rows 4..15 zero)
    short8 au[2][2];
#pragma unroll
    for (int ri = 0; ri < 2; ++ri)
#pragma unroll
      for (int kt = 0; kt < 2; ++kt)
        au[ri][kt] = (nlo < 4) ? *(const short8*)&sh_ub[ri][nlo][kt * 32 + quad * 8] : zero8;

#pragma unroll
    for (int ri = 0; ri < 2; ++ri) {
      // ---- Stage B: S_ri = silu(rb_ri @ Wr1) via MFMA -> sh_S (swizzled) ----
#pragma unroll
      for (int mtp = 0; mtp < 2; ++mtp) {
        f32x4 Cs[2][2];
#pragma unroll
        for (int mi = 0; mi < 2; ++mi)
#pragma unroll
          for (int nt = 0; nt < 2; ++nt) Cs[mi][nt] = (f32x4){0.f, 0.f, 0.f, 0.f};
#pragma unroll
        for (int mi = 0; mi < 2; ++mi) {
          int mt = mtp * 2 + mi;
          short8 afr = (quad == 0) ? *(const short8*)&sh_rbh[ri][mt * 16 + nlo][0] : zero8;
#pragma unroll
          for (int nt = 0; nt < 2; ++nt)
            Cs[mi][nt] = __builtin_amdgcn_mfma_f32_16x16x32_bf16(afr, bw[nt], Cs[mi][nt], 0, 0, 0);
        }
#pragma unroll
        for (int mi = 0; mi < 2; ++mi)
#pragma unroll
          for (int nt = 0; nt < 2; ++nt)
#pragma unroll
            for (int reg = 0; reg < 4; ++reg) {
              int s = (mtp * 2 + mi) * 16 + quad * 4 + reg;
              int c = w * 32 + nt * 16 + nlo;
              sh_S[s][SWZ(s, c)] = bf1(silu_f(Cs[mi][nt][reg]));
            }
      }
      __syncthreads();   // S_ri ready

      // ---- Main GEMM; M0 = C*h -> per-wave transposed tile (no barrier) ----
#pragma unroll
      for (int mt = 0; mt < 4; ++mt) {
        short8 afr[4];
        int s_a = mt * 16 + nlo;
#pragma unroll
        for (int kt = 0; kt < 4; ++kt)
          afr[kt] = *(const short8*)&sh_S[s_a][SWZ(s_a, kt * 32 + quad * 8)];
#pragma unroll
        for (int nt = 0; nt < 2; ++nt) {
          f32x4 C = {0.f, 0.f, 0.f, 0.f};
#pragma unroll
          for (int kt = 0; kt < 4; ++kt)
            C = __builtin_amdgcn_mfma_f32_16x16x32_bf16(afr[kt], bfr[kt][nt], C, 0, 0, 0);
          f32x4 m0 = C * hbv[mt][nt];               // pk-mul pairs
          u32x2 pk;
          pk.x = bf2(m0[0], m0[1]);
          pk.y = bf2(m0[2], m0[3]);
          *(u32x2*)&sh_M0T[w][nt * 16 + nlo][mt * 16 + quad * 4] = pk;  // own-wave tile
        }
      }
      // ---- U-GEMM: [a0;a1x;a1y;a1z](this wave's 32 cols) = U @ M0 ----
      {
        f32x4 Cu[2] = {{0, 0, 0, 0}, {0, 0, 0, 0}};
#pragma unroll
        for (int nt = 0; nt < 2; ++nt)
#pragma unroll
          for (int kt = 0; kt < 2; ++kt) {
            short8 bm = *(const short8*)&sh_M0T[w][nt * 16 + nlo][kt * 32 + quad * 8];
            Cu[nt] = __builtin_amdgcn_mfma_f32_16x16x32_bf16(au[ri][kt], bm, Cu[nt], 0, 0, 0);
          }
        if (quad == 0) {
#pragma unroll
          for (int nt = 0; nt < 2; ++nt) {
            size_t base = (size_t)(b * NN + rb0 + ri) * HH + w * 32 + nt * 16 + nlo;
#pragma unroll
            for (int reg = 0; reg < 4; ++reg)
              apout[(l * 4 + reg) * PLANE + base] = bf1(Cu[nt][reg]);
          }
        }
      }
      // protect sh_S (next StageB) and sh_rbh/sh_ub (next Stage A) overwrites
      if (!(pp == 1 && ri == 1)) __syncthreads();
    }
  }
}

// Final update + readout, 8 rows/block (grid 512), 10 MFMA GEMMs in-block.
// sh_a/sh_h/sh_q column-swizzled; staging via 16B loads/stores.
__global__ __launch_bounds__(256) void k_update_ro(
    const unsigned short* __restrict__ apbf, const float* __restrict__ hA,
    const unsigned short* __restrict__ Wpack,
    const float* __restrict__ fs, float* __restrict__ out) {
  __shared__ __align__(16) unsigned short sh_a[8][8][136];   // [0] aliased by q later
  __shared__ __align__(16) unsigned short sh_h[8][136];
  __shared__ float red[4][8][3];
  int tid = threadIdx.x, w = tid >> 6, lane = tid & 63;
  int nlo = lane & 15, quad = lane >> 4;
  int row0 = blockIdx.x * 8;
#pragma unroll
  for (int it = 0; it < 4; ++it) {
    int i2 = it * 256 + tid;           // 0..1023
    int p = i2 >> 7, rr = (i2 >> 4) & 7, c8 = (i2 & 15) * 8;
    *(ushort8*)&sh_a[p][rr][SWZ(rr, c8)] =
        *(const ushort8*)&apbf[p * PLANE + (size_t)(row0 + rr) * HH + c8];
  }
  f32x4 Ch[2];
#pragma unroll
  for (int nt = 0; nt < 2; ++nt)
#pragma unroll
    for (int reg = 0; reg < 4; ++reg)
      Ch[nt][reg] = (quad < 2)
          ? hA[(size_t)(row0 + quad * 4 + reg) * HH + w * 32 + nt * 16 + nlo] : 0.f;
  __syncthreads();
  gemm8(sh_a[0], Wpack + 2 * 16384, w, nlo, quad, Ch);   // + a0l0@Wupd0
  gemm8(sh_a[4], Wpack + 3 * 16384, w, nlo, quad, Ch);   // + a0l1@Wupd1
  f32x4 Cx[2] = {{0,0,0,0},{0,0,0,0}};
  f32x4 Cy[2] = {{0,0,0,0},{0,0,0,0}};
  f32x4 Cz[2] = {{0,0,0,0},{0,0,0,0}};
  gemm8(sh_a[1], Wpack + 4 * 16384, w, nlo, quad, Cx);
  gemm8(sh_a[5], Wpack + 5 * 16384, w, nlo, quad, Cx);
  gemm8(sh_a[2], Wpack + 4 * 16384, w, nlo, quad, Cy);
  gemm8(sh_a[6], Wpack + 5 * 16384, w, nlo, quad, Cy);
  gemm8(sh_a[3], Wpack + 4 * 16384, w, nlo, quad, Cz);
  gemm8(sh_a[7], Wpack + 5 * 16384, w, nlo, quad, Cz);
  if (quad < 2) {
#pragma unroll
    for (int nt = 0; nt < 2; ++nt)
#pragma unroll
      for (int reg = 0; reg < 4; ++reg) {
        int row = quad * 4 + reg, c = w * 32 + nt * 16 + nlo;
        sh_h[row][SWZ(row, c)] = bf1(Ch[nt][reg]);
      }
  }
  __syncthreads();   // sh_h ready; sh_a reads done -> sh_a[0] free to alias
  unsigned short (*sh_q)[136] = sh_a[0];
  f32x4 Cq[2] = {{0,0,0,0},{0,0,0,0}};
  gemm8(sh_h, Wpack + 6 * 16384, w, nlo, quad, Cq);
  if (quad < 2) {
#pragma unroll
    for (int nt = 0; nt < 2; ++nt)
#pragma unroll
      for (int reg = 0; reg < 4; ++reg) {
        int row = quad * 4 + reg, c = w * 32 + nt * 16 + nlo;
        sh_q[row][SWZ(row, c)] = bf1(silu_f(Cq[nt][reg]));
      }
  }
  __syncthreads();
  f32x4 Cg[2] = {{0,0,0,0},{0,0,0,0}};
  gemm8(sh_q, Wpack + 7 * 16384, w, nlo, quad, Cg);
  float pr[3][4];
#pragma unroll
  for (int d = 0; d < 3; ++d)
#pragma unroll
    for (int reg = 0; reg < 4; ++reg) pr[d][reg] = 0.f;
#pragma unroll
  for (int nt = 0; nt < 2; ++nt)
#pragma unroll
    for (int reg = 0; reg < 4; ++reg) {
      float gv = Cg[nt][reg];
      pr[0][reg] += gv * Cx[nt][reg];
      pr[1][reg] += gv * Cy[nt][reg];
      pr[2][reg] += gv * Cz[nt][reg];
    }
#pragma unroll
  for (int off = 1; off < 16; off <<= 1)
#pragma unroll
    for (int d = 0; d < 3; ++d)
#pragma unroll
      for (int reg = 0; reg < 4; ++reg)
        pr[d][reg] += __shfl_xor(pr[d][reg], off);
  if (nlo == 0 && quad < 2) {
#pragma unroll
    for (int d = 0; d < 3; ++d)
#pragma unroll
      for (int reg = 0; reg < 4; ++reg)
        red[w][quad * 4 + reg][d] = pr[d][reg];
  }
  __syncthreads();
  if (tid < 24) {
    int row = tid / 3, d = tid % 3;
    float s = red[0][row][d] + red[1][row][d] + red[2][row][d] + red[3][row][d];
    out[(size_t)(row0 + row) * 3 + d] = s * fs[0];
  }
}

extern "C" void kernel_launch(void* const* d_in, const int* in_sizes, int n_in,
                              void* d_out, int out_size, void* d_ws, size_t ws_size,
                              hipStream_t stream) {
  const float* pos  = (const float*)d_in[0];
  const int*   z    = (const int*)d_in[1];
  const float* gf   = (const float*)d_in[2];
  const float* emb  = (const float*)d_in[3];
  const float* Wt   = (const float*)d_in[4];
  const float* Wr1  = (const float*)d_in[5];
  const float* Wr2  = (const float*)d_in[6];
  const float* Wupd = (const float*)d_in[7];
  const float* Wmix = (const float*)d_in[8];
  const float* Wg1  = (const float*)d_in[9];
  const float* Wg2  = (const float*)d_in[10];
  const float* fs   = (const float*)d_in[11];
  float* out = (float*)d_out;

  float* ws = (float*)d_ws;
  float* hA = ws;                                         // 2 MB
  unsigned short* apbf = (unsigned short*)(ws + PLANE);   // 8 bf16 planes = 8 MB
  unsigned short* Wpack = (unsigned short*)(ws + 5 * PLANE);  // 272 KB

  k_init<<<dim3(256), dim3(256), 0, stream>>>(emb, z, gf, Wt, Wr1, Wr2, Wupd,
                                              Wmix, Wg1, Wg2, hA, Wpack);
  k_layer<<<dim3(BB * 16), dim3(256), 0, stream>>>(pos, hA, apbf, apbf, Wpack, 0);
  k_layer<<<dim3(BB * 16), dim3(256), 0, stream>>>(pos, hA, apbf, apbf, Wpack, 1);
  k_update_ro<<<dim3(512), dim3(256), 0, stream>>>(apbf, hA, Wpack, fs, out);
}

// Round 8
// 141.292 us; speedup vs baseline: 1.5751x; 1.0722x over previous
//
#include <hip/hip_runtime.h>
#include <math.h>

#define NN 64      // nodes per graph
#define HH 128     // hidden channels
#define NBB 8      // bessel basis
#define TT 32      // time embedding dim
#define BB 64      // batch
#define NROW (BB * NN)        // 4096 total rows
#define PLANE ((size_t)NROW * HH)   // 524288
#define WR1OFF (8 * 16384)    // Wr1 B-frag slabs in Wpack (2 x 4096)

typedef __attribute__((ext_vector_type(8))) short short8;
typedef __attribute__((ext_vector_type(4))) float f32x4;
typedef __attribute__((ext_vector_type(2))) unsigned int u32x2;

__device__ __forceinline__ float silu_f(float x) {
  return x * __builtin_amdgcn_rcpf(1.0f + __expf(-x));
}

__device__ __forceinline__ unsigned short bf1(float x) {
  __bf16 h = (__bf16)x;
  return *(unsigned short*)&h;
}
__device__ __forceinline__ unsigned bf2(float lo, float hi) {
  return (unsigned)bf1(lo) | ((unsigned)bf1(hi) << 16);
}

// 8-row MFMA GEMM tile: A rows 8..15 zero. C map: row=quad*4+reg (<8), col=w*32+nt*16+nlo.
__device__ __forceinline__ void gemm8(
    const unsigned short (*sA)[136], const unsigned short* __restrict__ Bp,
    int w, int nlo, int quad, f32x4 C[2]) {
  const short8 z8 = {0, 0, 0, 0, 0, 0, 0, 0};
  short8 afr[4];
#pragma unroll
  for (int kt = 0; kt < 4; ++kt)
    afr[kt] = (nlo < 8) ? *(const short8*)&sA[nlo][kt * 32 + quad * 8] : z8;
#pragma unroll
  for (int nt = 0; nt < 2; ++nt)
#pragma unroll
    for (int kt = 0; kt < 4; ++kt) {
      short8 bfr = *(const short8*)&Bp[((kt * 128 + w * 32 + nt * 16 + nlo) * 4 + quad) * 8];
      C[nt] = __builtin_amdgcn_mfma_f32_16x16x32_bf16(afr[kt], bfr, C[nt], 0, 0, 0);
    }
}

// Grid 256. Pack all weights -> bf16 MFMA-B-frag order; blocks<64 init h. (R2-exact)
__global__ __launch_bounds__(256) void k_init(
    const float* __restrict__ emb, const int* __restrict__ z,
    const float* __restrict__ gf, const float* __restrict__ Wt,
    const float* __restrict__ Wr1, const float* __restrict__ Wr2,
    const float* __restrict__ Wupd, const float* __restrict__ Wmix,
    const float* __restrict__ Wg1, const float* __restrict__ Wg2,
    float* __restrict__ h, unsigned short* __restrict__ Wpack) {
  __shared__ float tvec[HH];
  __shared__ int sz[NN];
  int b4 = blockIdx.x, tid = threadIdx.x;
  {
    int p2 = b4 * 256 + tid;
    int p = p2 * 2;
    int m = p >> 14;
    int j = p & 7;
    int q = (p >> 3) & 3;
    int n = (p >> 5) & 127;
    int kt = (p >> 12) & 3;
    int k = kt * 32 + q * 8 + j;
    const float* src;
    int base;
    if (m < 2) { src = Wr2; base = m * 16384; }
    else if (m < 4) { src = Wupd; base = (m - 2) * 16384; }
    else if (m < 6) { src = Wmix; base = (m - 4) * 16384; }
    else if (m == 6) { src = Wg1; base = 0; }
    else { src = Wg2; base = 0; }
    float v0 = src[base + k * 128 + n];
    float v1 = src[base + (k + 1) * 128 + n];
    *(unsigned*)&Wpack[p] = bf2(v0, v1);
  }
  if (tid < 32) {
    int e = b4 * 32 + tid;
    int l = e >> 12, p = e & 4095;
    int n = p >> 5, q = (p >> 3) & 3, j = p & 7;
    float val = (q == 0) ? Wr1[l * NBB * HH + j * HH + n] : 0.f;
    Wpack[WR1OFF + l * 4096 + p] = bf1(val);
  }
  if (b4 < 64) {
    int b = b4;
    if (tid < NN) sz[tid] = z[b * NN + tid];
    if (tid < HH) {
      float acc = 0.f;
#pragma unroll
      for (int k = 0; k < TT; ++k) acc += gf[b * TT + k] * Wt[k * HH + tid];
      tvec[tid] = acc;
    }
    __syncthreads();
    for (int i = tid; i < NN * HH; i += 256) {
      int n = i >> 7, c = i & 127;
      h[(size_t)b * NN * HH + i] = emb[sz[n] * HH + c] + tvec[c];
    }
  }
}

// Layer 0 only (R2-exact body, l=0 specialized). Grid BB*16 = 1024, 4 receivers/block.
__global__ __launch_bounds__(256) void k_layer0(
    const float* __restrict__ pos, const float* __restrict__ hA,
    unsigned short* __restrict__ apout, const unsigned short* __restrict__ Wpack) {
  __shared__ __align__(16) unsigned short sh_S[NN][136];     // 17408 B
  __shared__ __align__(16) unsigned short sh_M0T[4][32][72]; // 18432 B
  __shared__ __align__(16) unsigned short sh_rbh[2][NN][8];  // 2048 B
  __shared__ __align__(16) unsigned short sh_ub[2][4][NN];   // 1024 B

  int blk = blockIdx.x;
  int b = blk >> 4, rp4 = blk & 15;
  int r0 = rp4 * 4;
  int tid = threadIdx.x;
  int w = tid >> 6, lane = tid & 63;
  int nlo = lane & 15, quad = lane >> 4;

  f32x4 hbv[4][2];
#pragma unroll
  for (int mt = 0; mt < 4; ++mt)
#pragma unroll
    for (int nt = 0; nt < 2; ++nt)
#pragma unroll
      for (int reg = 0; reg < 4; ++reg)
        hbv[mt][nt][reg] =
            hA[((size_t)b * NN + mt * 16 + quad * 4 + reg) * HH + w * 32 + nt * 16 + nlo];

  const unsigned short* Wr1p = Wpack + WR1OFF;
  short8 bw[2];
#pragma unroll
  for (int nt = 0; nt < 2; ++nt)
    bw[nt] = *(const short8*)&Wr1p[((w * 32 + nt * 16 + nlo) * 4 + quad) * 8];
  const unsigned short* Bbase = Wpack;
  short8 bfr[4][2];
#pragma unroll
  for (int kt = 0; kt < 4; ++kt)
#pragma unroll
    for (int nt = 0; nt < 2; ++nt)
      bfr[kt][nt] = *(const short8*)&Bbase[((kt * 128 + w * 32 + nt * 16 + nlo) * 4 + quad) * 8];

  const short8 zero8 = {0, 0, 0, 0, 0, 0, 0, 0};

#pragma unroll
  for (int pp = 0; pp < 2; ++pp) {
    int rb0 = r0 + pp * 2;
    {
      int s = tid & 63;
      int ksel = (tid >> 6) & 1;
      int ri = (tid >> 7) & 1;
      int r = rb0 + ri;
      const float* pb = pos + b * NN * 3;
      float dx = pb[r * 3 + 0] - pb[s * 3 + 0];
      float dy = pb[r * 3 + 1] - pb[s * 3 + 1];
      float dz = pb[r * 3 + 2] - pb[s * 3 + 2];
      float rr = sqrtf(dx * dx + dy * dy + dz * dz + 1e-12f);
      float inv = __builtin_amdgcn_rcpf(rr);
      const float invAvg = 1.0f / 63.0f;
      if (ksel == 0) {
        float ia = inv * invAvg;
        sh_ub[ri][1][s] = bf1(dx * ia);
        sh_ub[ri][2][s] = bf1(dy * ia);
        sh_ub[ri][3][s] = bf1(dz * ia);
      } else {
        sh_ub[ri][0][s] = bf1(invAvg);
      }
      const float PI_OVER_5 = 0.628318530717958647692f;
      float fc = (s != r && rr < 5.0f) ? 0.5f * (__cosf(PI_OVER_5 * rr) + 1.0f) : 0.0f;
      float base = PI_OVER_5 * rr;
      float sc = inv * fc;
      int k0 = ksel * 4;
      float v0 = __sinf((float)(k0 + 1) * base) * sc;
      float v1 = __sinf((float)(k0 + 2) * base) * sc;
      float v2 = __sinf((float)(k0 + 3) * base) * sc;
      float v3 = __sinf((float)(k0 + 4) * base) * sc;
      *(unsigned*)&sh_rbh[ri][s][k0]     = bf2(v0, v1);
      *(unsigned*)&sh_rbh[ri][s][k0 + 2] = bf2(v2, v3);
    }
    __syncthreads();

    short8 au[2][2];
#pragma unroll
    for (int ri = 0; ri < 2; ++ri)
#pragma unroll
      for (int kt = 0; kt < 2; ++kt)
        au[ri][kt] = (nlo < 4) ? *(const short8*)&sh_ub[ri][nlo][kt * 32 + quad * 8] : zero8;

#pragma unroll
    for (int ri = 0; ri < 2; ++ri) {
#pragma unroll
      for (int mtp = 0; mtp < 2; ++mtp) {
        f32x4 Cs[2][2];
#pragma unroll
        for (int mi = 0; mi < 2; ++mi)
#pragma unroll
          for (int nt = 0; nt < 2; ++nt) Cs[mi][nt] = (f32x4){0.f, 0.f, 0.f, 0.f};
#pragma unroll
        for (int mi = 0; mi < 2; ++mi) {
          int mt = mtp * 2 + mi;
          short8 afr = (quad == 0) ? *(const short8*)&sh_rbh[ri][mt * 16 + nlo][0] : zero8;
#pragma unroll
          for (int nt = 0; nt < 2; ++nt)
            Cs[mi][nt] = __builtin_amdgcn_mfma_f32_16x16x32_bf16(afr, bw[nt], Cs[mi][nt], 0, 0, 0);
        }
#pragma unroll
        for (int mi = 0; mi < 2; ++mi)
#pragma unroll
          for (int nt = 0; nt < 2; ++nt)
#pragma unroll
            for (int reg = 0; reg < 4; ++reg) {
              int s = (mtp * 2 + mi) * 16 + quad * 4 + reg;
              int c = w * 32 + nt * 16 + nlo;
              sh_S[s][c] = bf1(silu_f(Cs[mi][nt][reg]));
            }
      }
      __syncthreads();

#pragma unroll
      for (int mt = 0; mt < 4; ++mt) {
        short8 afr[4];
        int s_a = mt * 16 + nlo;
#pragma unroll
        for (int kt = 0; kt < 4; ++kt)
          afr[kt] = *(const short8*)&sh_S[s_a][kt * 32 + quad * 8];
#pragma unroll
        for (int nt = 0; nt < 2; ++nt) {
          f32x4 C = {0.f, 0.f, 0.f, 0.f};
#pragma unroll
          for (int kt = 0; kt < 4; ++kt)
            C = __builtin_amdgcn_mfma_f32_16x16x32_bf16(afr[kt], bfr[kt][nt], C, 0, 0, 0);
          f32x4 m0 = C * hbv[mt][nt];
          u32x2 pk;
          pk.x = bf2(m0[0], m0[1]);
          pk.y = bf2(m0[2], m0[3]);
          *(u32x2*)&sh_M0T[w][nt * 16 + nlo][mt * 16 + quad * 4] = pk;
        }
      }
      {
        f32x4 Cu[2] = {{0, 0, 0, 0}, {0, 0, 0, 0}};
#pragma unroll
        for (int nt = 0; nt < 2; ++nt)
#pragma unroll
          for (int kt = 0; kt < 2; ++kt) {
            short8 bm = *(const short8*)&sh_M0T[w][nt * 16 + nlo][kt * 32 + quad * 8];
            Cu[nt] = __builtin_amdgcn_mfma_f32_16x16x32_bf16(au[ri][kt], bm, Cu[nt], 0, 0, 0);
          }
        if (quad == 0) {
#pragma unroll
          for (int nt = 0; nt < 2; ++nt) {
            size_t base = (size_t)(b * NN + rb0 + ri) * HH + w * 32 + nt * 16 + nlo;
#pragma unroll
            for (int reg = 0; reg < 4; ++reg)
              apout[reg * PLANE + base] = bf1(Cu[nt][reg]);
          }
        }
      }
      if (!(pp == 1 && ri == 1)) __syncthreads();
    }
  }
}

// Fused layer-1 + update/readout. Grid 512: block blk = (b = blk>>3, u8 = blk&7)
// computes receivers [u8*8, u8*8+8) of graph b (= global rows [blk*8, blk*8+8))
// then updates/reads out exactly those rows. All cross-block inputs (a0_l0 plane,
// planes 0-3, hA) come from PRIOR LAUNCHES (coherent via launch boundary); planes
// 4-7 are produced and consumed by the SAME block (same-XCD L2, safe).
__global__ __launch_bounds__(256) void k_fused(
    const float* __restrict__ pos, const float* __restrict__ hA,
    unsigned short* __restrict__ apbf, const unsigned short* __restrict__ Wpack,
    const float* __restrict__ fs, float* __restrict__ out) {
  __shared__ __align__(16) unsigned char smem[38912];
  unsigned short (*sh_S)[136]      = (unsigned short (*)[136])smem;              // 17408 B
  unsigned short (*sh_M0T)[32][72] = (unsigned short (*)[32][72])(smem + 17408); // 18432 B
  unsigned short (*sh_rbh)[NN][8]  = (unsigned short (*)[NN][8])(smem + 35840);  // 2048 B
  unsigned short (*sh_ub)[4][NN]   = (unsigned short (*)[4][NN])(smem + 37888);  // 1024 B

  int blk = blockIdx.x;
  int b = blk >> 3, u8 = blk & 7;
  int tid = threadIdx.x;
  int w = tid >> 6, lane = tid & 63;
  int nlo = lane & 15, quad = lane >> 4;
  const short8 zero8 = {0, 0, 0, 0, 0, 0, 0, 0};

  // ---- hbv: graph h in C-reg layout ----
  f32x4 hbv[4][2];
#pragma unroll
  for (int mt = 0; mt < 4; ++mt)
#pragma unroll
    for (int nt = 0; nt < 2; ++nt)
#pragma unroll
      for (int reg = 0; reg < 4; ++reg)
        hbv[mt][nt][reg] =
            hA[((size_t)b * NN + mt * 16 + quad * 4 + reg) * HH + w * 32 + nt * 16 + nlo];

  // ---- stage a0_l0 (prior launch) and apply hbv += a0_l0 @ Wupd0 ----
  for (int i = tid; i < NN * 64; i += 256) {
    int s = i >> 6, c2 = (i & 63) * 2;
    *(unsigned*)&sh_S[s][c2] =
        *(const unsigned*)&apbf[((size_t)b * NN + s) * HH + c2];
  }
  __syncthreads();
  {
    const unsigned short* Bu = Wpack + 2 * 16384;
#pragma unroll
    for (int mt = 0; mt < 4; ++mt) {
      short8 afr[4];
#pragma unroll
      for (int kt = 0; kt < 4; ++kt)
        afr[kt] = *(const short8*)&sh_S[mt * 16 + nlo][kt * 32 + quad * 8];
#pragma unroll
      for (int nt = 0; nt < 2; ++nt)
#pragma unroll
        for (int kt = 0; kt < 4; ++kt) {
          short8 bfr2 = *(const short8*)&Bu[((kt * 128 + w * 32 + nt * 16 + nlo) * 4 + quad) * 8];
          hbv[mt][nt] = __builtin_amdgcn_mfma_f32_16x16x32_bf16(afr[kt], bfr2, hbv[mt][nt], 0, 0, 0);
        }
    }
  }
  __syncthreads();   // sh_S reads done before Stage B overwrites

  // ---- layer-1 fragment hoists ----
  const unsigned short* Wr1p = Wpack + WR1OFF + 4096;
  short8 bw[2];
#pragma unroll
  for (int nt = 0; nt < 2; ++nt)
    bw[nt] = *(const short8*)&Wr1p[((w * 32 + nt * 16 + nlo) * 4 + quad) * 8];
  const unsigned short* Bbase = Wpack + 16384;
  short8 bfr[4][2];
#pragma unroll
  for (int kt = 0; kt < 4; ++kt)
#pragma unroll
    for (int nt = 0; nt < 2; ++nt)
      bfr[kt][nt] = *(const short8*)&Bbase[((kt * 128 + w * 32 + nt * 16 + nlo) * 4 + quad) * 8];

  for (int unit = 0; unit < 2; ++unit) {
    int r0 = (u8 * 2 + unit) * 4;
#pragma unroll
    for (int pp = 0; pp < 2; ++pp) {
      int rb0 = r0 + pp * 2;
      {
        int s = tid & 63;
        int ksel = (tid >> 6) & 1;
        int ri = (tid >> 7) & 1;
        int r = rb0 + ri;
        const float* pb = pos + b * NN * 3;
        float dx = pb[r * 3 + 0] - pb[s * 3 + 0];
        float dy = pb[r * 3 + 1] - pb[s * 3 + 1];
        float dz = pb[r * 3 + 2] - pb[s * 3 + 2];
        float rr = sqrtf(dx * dx + dy * dy + dz * dz + 1e-12f);
        float inv = __builtin_amdgcn_rcpf(rr);
        const float invAvg = 1.0f / 63.0f;
        if (ksel == 0) {
          float ia = inv * invAvg;
          sh_ub[ri][1][s] = bf1(dx * ia);
          sh_ub[ri][2][s] = bf1(dy * ia);
          sh_ub[ri][3][s] = bf1(dz * ia);
        } else {
          sh_ub[ri][0][s] = bf1(invAvg);
        }
        const float PI_OVER_5 = 0.628318530717958647692f;
        float fc = (s != r && rr < 5.0f) ? 0.5f * (__cosf(PI_OVER_5 * rr) + 1.0f) : 0.0f;
        float base = PI_OVER_5 * rr;
        float sc = inv * fc;
        int k0 = ksel * 4;
        float v0 = __sinf((float)(k0 + 1) * base) * sc;
        float v1 = __sinf((float)(k0 + 2) * base) * sc;
        float v2 = __sinf((float)(k0 + 3) * base) * sc;
        float v3 = __sinf((float)(k0 + 4) * base) * sc;
        *(unsigned*)&sh_rbh[ri][s][k0]     = bf2(v0, v1);
        *(unsigned*)&sh_rbh[ri][s][k0 + 2] = bf2(v2, v3);
      }
      __syncthreads();

      short8 au[2][2];
#pragma unroll
      for (int ri = 0; ri < 2; ++ri)
#pragma unroll
        for (int kt = 0; kt < 2; ++kt)
          au[ri][kt] = (nlo < 4) ? *(const short8*)&sh_ub[ri][nlo][kt * 32 + quad * 8] : zero8;

#pragma unroll
      for (int ri = 0; ri < 2; ++ri) {
#pragma unroll
        for (int mtp = 0; mtp < 2; ++mtp) {
          f32x4 Cs[2][2];
#pragma unroll
          for (int mi = 0; mi < 2; ++mi)
#pragma unroll
            for (int nt = 0; nt < 2; ++nt) Cs[mi][nt] = (f32x4){0.f, 0.f, 0.f, 0.f};
#pragma unroll
          for (int mi = 0; mi < 2; ++mi) {
            int mt = mtp * 2 + mi;
            short8 afr = (quad == 0) ? *(const short8*)&sh_rbh[ri][mt * 16 + nlo][0] : zero8;
#pragma unroll
            for (int nt = 0; nt < 2; ++nt)
              Cs[mi][nt] = __builtin_amdgcn_mfma_f32_16x16x32_bf16(afr, bw[nt], Cs[mi][nt], 0, 0, 0);
          }
#pragma unroll
          for (int mi = 0; mi < 2; ++mi)
#pragma unroll
            for (int nt = 0; nt < 2; ++nt)
#pragma unroll
              for (int reg = 0; reg < 4; ++reg) {
                int s = (mtp * 2 + mi) * 16 + quad * 4 + reg;
                int c = w * 32 + nt * 16 + nlo;
                sh_S[s][c] = bf1(silu_f(Cs[mi][nt][reg]));
              }
        }
        __syncthreads();

#pragma unroll
        for (int mt = 0; mt < 4; ++mt) {
          short8 afr[4];
          int s_a = mt * 16 + nlo;
#pragma unroll
          for (int kt = 0; kt < 4; ++kt)
            afr[kt] = *(const short8*)&sh_S[s_a][kt * 32 + quad * 8];
#pragma unroll
          for (int nt = 0; nt < 2; ++nt) {
            f32x4 C = {0.f, 0.f, 0.f, 0.f};
#pragma unroll
            for (int kt = 0; kt < 4; ++kt)
              C = __builtin_amdgcn_mfma_f32_16x16x32_bf16(afr[kt], bfr[kt][nt], C, 0, 0, 0);
            f32x4 m0 = C * hbv[mt][nt];
            u32x2 pk;
            pk.x = bf2(m0[0], m0[1]);
            pk.y = bf2(m0[2], m0[3]);
            *(u32x2*)&sh_M0T[w][nt * 16 + nlo][mt * 16 + quad * 4] = pk;
          }
        }
        {
          f32x4 Cu[2] = {{0, 0, 0, 0}, {0, 0, 0, 0}};
#pragma unroll
          for (int nt = 0; nt < 2; ++nt)
#pragma unroll
            for (int kt = 0; kt < 2; ++kt) {
              short8 bm = *(const short8*)&sh_M0T[w][nt * 16 + nlo][kt * 32 + quad * 8];
              Cu[nt] = __builtin_amdgcn_mfma_f32_16x16x32_bf16(au[ri][kt], bm, Cu[nt], 0, 0, 0);
            }
          if (quad == 0) {
#pragma unroll
            for (int nt = 0; nt < 2; ++nt) {
              size_t base = (size_t)(b * NN + rb0 + ri) * HH + w * 32 + nt * 16 + nlo;
#pragma unroll
              for (int reg = 0; reg < 4; ++reg)
                apbf[(4 + reg) * PLANE + base] = bf1(Cu[nt][reg]);
            }
          }
        }
        __syncthreads();   // LDS safe to overwrite (also before update aliasing)
      }
    }
  }

  // ---- update + readout for rows [blk*8, blk*8+8) (all inputs block-local/prior-launch) ----
  {
    unsigned short (*sh_a)[8][136] = (unsigned short (*)[8][136])smem;           // 17408 B
    unsigned short (*sh_h)[136]    = (unsigned short (*)[136])(smem + 17408);    // 2176 B
    float (*red)[8][3]             = (float (*)[8][3])(smem + 17408 + 2176);     // 384 B
    int row0 = blk * 8;
    for (int i = tid; i < 8 * 8 * 64; i += 256) {
      int p = i >> 9, rr = (i >> 6) & 7, c2 = (i & 63) * 2;
      *(unsigned*)&sh_a[p][rr][c2] =
          *(const unsigned*)&apbf[p * PLANE + (size_t)(row0 + rr) * HH + c2];
    }
    f32x4 Ch[2];
#pragma unroll
    for (int nt = 0; nt < 2; ++nt)
#pragma unroll
      for (int reg = 0; reg < 4; ++reg)
        Ch[nt][reg] = (quad < 2)
            ? hA[(size_t)(row0 + quad * 4 + reg) * HH + w * 32 + nt * 16 + nlo] : 0.f;
    __syncthreads();
    gemm8(sh_a[0], Wpack + 2 * 16384, w, nlo, quad, Ch);   // + a0l0@Wupd0
    gemm8(sh_a[4], Wpack + 3 * 16384, w, nlo, quad, Ch);   // + a0l1@Wupd1
    f32x4 Cx[2] = {{0,0,0,0},{0,0,0,0}};
    f32x4 Cy[2] = {{0,0,0,0},{0,0,0,0}};
    f32x4 Cz[2] = {{0,0,0,0},{0,0,0,0}};
    gemm8(sh_a[1], Wpack + 4 * 16384, w, nlo, quad, Cx);
    gemm8(sh_a[5], Wpack + 5 * 16384, w, nlo, quad, Cx);
    gemm8(sh_a[2], Wpack + 4 * 16384, w, nlo, quad, Cy);
    gemm8(sh_a[6], Wpack + 5 * 16384, w, nlo, quad, Cy);
    gemm8(sh_a[3], Wpack + 4 * 16384, w, nlo, quad, Cz);
    gemm8(sh_a[7], Wpack + 5 * 16384, w, nlo, quad, Cz);
    if (quad < 2) {
#pragma unroll
      for (int nt = 0; nt < 2; ++nt)
#pragma unroll
        for (int reg = 0; reg < 4; ++reg)
          sh_h[quad * 4 + reg][w * 32 + nt * 16 + nlo] = bf1(Ch[nt][reg]);
    }
    __syncthreads();
    unsigned short (*sh_q)[136] = sh_a[0];
    f32x4 Cq[2] = {{0,0,0,0},{0,0,0,0}};
    gemm8(sh_h, Wpack + 6 * 16384, w, nlo, quad, Cq);
    if (quad < 2) {
#pragma unroll
      for (int nt = 0; nt < 2; ++nt)
#pragma unroll
        for (int reg = 0; reg < 4; ++reg)
          sh_q[quad * 4 + reg][w * 32 + nt * 16 + nlo] = bf1(silu_f(Cq[nt][reg]));
    }
    __syncthreads();
    f32x4 Cg[2] = {{0,0,0,0},{0,0,0,0}};
    gemm8(sh_q, Wpack + 7 * 16384, w, nlo, quad, Cg);
    float pr[3][4];
#pragma unroll
    for (int d = 0; d < 3; ++d)
#pragma unroll
      for (int reg = 0; reg < 4; ++reg) pr[d][reg] = 0.f;
#pragma unroll
    for (int nt = 0; nt < 2; ++nt)
#pragma unroll
      for (int reg = 0; reg < 4; ++reg) {
        float gv = Cg[nt][reg];
        pr[0][reg] += gv * Cx[nt][reg];
        pr[1][reg] += gv * Cy[nt][reg];
        pr[2][reg] += gv * Cz[nt][reg];
      }
#pragma unroll
    for (int off = 1; off < 16; off <<= 1)
#pragma unroll
      for (int d = 0; d < 3; ++d)
#pragma unroll
        for (int reg = 0; reg < 4; ++reg)
          pr[d][reg] += __shfl_xor(pr[d][reg], off);
    if (nlo == 0 && quad < 2) {
#pragma unroll
      for (int d = 0; d < 3; ++d)
#pragma unroll
        for (int reg = 0; reg < 4; ++reg)
          red[w][quad * 4 + reg][d] = pr[d][reg];
    }
    __syncthreads();
    if (tid < 24) {
      int row = tid / 3, d = tid % 3;
      float s = red[0][row][d] + red[1][row][d] + red[2][row][d] + red[3][row][d];
      out[(size_t)(row0 + row) * 3 + d] = s * fs[0];
    }
  }
}

extern "C" void kernel_launch(void* const* d_in, const int* in_sizes, int n_in,
                              void* d_out, int out_size, void* d_ws, size_t ws_size,
                              hipStream_t stream) {
  const float* pos  = (const float*)d_in[0];
  const int*   z    = (const int*)d_in[1];
  const float* gf   = (const float*)d_in[2];
  const float* emb  = (const float*)d_in[3];
  const float* Wt   = (const float*)d_in[4];
  const float* Wr1  = (const float*)d_in[5];
  const float* Wr2  = (const float*)d_in[6];
  const float* Wupd = (const float*)d_in[7];
  const float* Wmix = (const float*)d_in[8];
  const float* Wg1  = (const float*)d_in[9];
  const float* Wg2  = (const float*)d_in[10];
  const float* fs   = (const float*)d_in[11];
  float* out = (float*)d_out;

  float* ws = (float*)d_ws;
  float* hA = ws;                                         // 2 MB
  unsigned short* apbf = (unsigned short*)(ws + PLANE);   // 8 bf16 planes = 8 MB
  unsigned short* Wpack = (unsigned short*)(ws + 5 * PLANE);  // 272 KB

  k_init<<<dim3(256), dim3(256), 0, stream>>>(emb, z, gf, Wt, Wr1, Wr2, Wupd,
                                              Wmix, Wg1, Wg2, hA, Wpack);
  k_layer0<<<dim3(BB * 16), dim3(256), 0, stream>>>(pos, hA, apbf, Wpack);
  k_fused<<<dim3(512), dim3(256), 0, stream>>>(pos, hA, apbf, Wpack, fs, out);
}

// Round 9
// 137.955 us; speedup vs baseline: 1.6132x; 1.0242x over previous
//
#include <hip/hip_runtime.h>
#include <math.h>

#define NN 64      // nodes per graph
#define HH 128     // hidden channels
#define NBB 8      // bessel basis
#define TT 32      // time embedding dim
#define BB 64      // batch
#define NROW (BB * NN)        // 4096 total rows
#define PLANE ((size_t)NROW * HH)   // 524288
#define WR1OFF (8 * 16384)    // Wr1 B-frag slabs in Wpack (2 x 4096)

typedef __attribute__((ext_vector_type(8))) short short8;
typedef __attribute__((ext_vector_type(4))) float f32x4;
typedef __attribute__((ext_vector_type(2))) unsigned int u32x2;

__device__ __forceinline__ float silu_f(float x) {
  return x * __builtin_amdgcn_rcpf(1.0f + __expf(-x));
}

__device__ __forceinline__ unsigned short bf1(float x) {
  __bf16 h = (__bf16)x;
  return *(unsigned short*)&h;
}
__device__ __forceinline__ unsigned bf2(float lo, float hi) {
  return (unsigned)bf1(lo) | ((unsigned)bf1(hi) << 16);
}

// 8-row MFMA GEMM tile: A rows 8..15 zero. C map: row=quad*4+reg (<8), col=w*32+nt*16+nlo.
__device__ __forceinline__ void gemm8(
    const unsigned short (*sA)[136], const unsigned short* __restrict__ Bp,
    int w, int nlo, int quad, f32x4 C[2]) {
  const short8 z8 = {0, 0, 0, 0, 0, 0, 0, 0};
  short8 afr[4];
#pragma unroll
  for (int kt = 0; kt < 4; ++kt)
    afr[kt] = (nlo < 8) ? *(const short8*)&sA[nlo][kt * 32 + quad * 8] : z8;
#pragma unroll
  for (int nt = 0; nt < 2; ++nt)
#pragma unroll
    for (int kt = 0; kt < 4; ++kt) {
      short8 bfr = *(const short8*)&Bp[((kt * 128 + w * 32 + nt * 16 + nlo) * 4 + quad) * 8];
      C[nt] = __builtin_amdgcn_mfma_f32_16x16x32_bf16(afr[kt], bfr, C[nt], 0, 0, 0);
    }
}

// Grid 256. Pack all weights -> bf16 MFMA-B-frag order; blocks<64 init h. (R2-exact)
__global__ __launch_bounds__(256) void k_init(
    const float* __restrict__ emb, const int* __restrict__ z,
    const float* __restrict__ gf, const float* __restrict__ Wt,
    const float* __restrict__ Wr1, const float* __restrict__ Wr2,
    const float* __restrict__ Wupd, const float* __restrict__ Wmix,
    const float* __restrict__ Wg1, const float* __restrict__ Wg2,
    float* __restrict__ h, unsigned short* __restrict__ Wpack) {
  __shared__ float tvec[HH];
  __shared__ int sz[NN];
  int b4 = blockIdx.x, tid = threadIdx.x;
  {
    int p2 = b4 * 256 + tid;
    int p = p2 * 2;
    int m = p >> 14;
    int j = p & 7;
    int q = (p >> 3) & 3;
    int n = (p >> 5) & 127;
    int kt = (p >> 12) & 3;
    int k = kt * 32 + q * 8 + j;
    const float* src;
    int base;
    if (m < 2) { src = Wr2; base = m * 16384; }
    else if (m < 4) { src = Wupd; base = (m - 2) * 16384; }
    else if (m < 6) { src = Wmix; base = (m - 4) * 16384; }
    else if (m == 6) { src = Wg1; base = 0; }
    else { src = Wg2; base = 0; }
    float v0 = src[base + k * 128 + n];
    float v1 = src[base + (k + 1) * 128 + n];
    *(unsigned*)&Wpack[p] = bf2(v0, v1);
  }
  if (tid < 32) {
    int e = b4 * 32 + tid;
    int l = e >> 12, p = e & 4095;
    int n = p >> 5, q = (p >> 3) & 3, j = p & 7;
    float val = (q == 0) ? Wr1[l * NBB * HH + j * HH + n] : 0.f;
    Wpack[WR1OFF + l * 4096 + p] = bf1(val);
  }
  if (b4 < 64) {
    int b = b4;
    if (tid < NN) sz[tid] = z[b * NN + tid];
    if (tid < HH) {
      float acc = 0.f;
#pragma unroll
      for (int k = 0; k < TT; ++k) acc += gf[b * TT + k] * Wt[k * HH + tid];
      tvec[tid] = acc;
    }
    __syncthreads();
    for (int i = tid; i < NN * HH; i += 256) {
      int n = i >> 7, c = i & 127;
      h[(size_t)b * NN * HH + i] = emb[sz[n] * HH + c] + tvec[c];
    }
  }
}

// Layer 0. Grid BB*16 = 1024, 4 receivers/block. Single Stage-A phase covers all
// 4 receivers (thread = (receiver ri4, sender s), 8 sins each -- same total trig,
// one barrier instead of two phases).
__global__ __launch_bounds__(256) void k_layer0(
    const float* __restrict__ pos, const float* __restrict__ hA,
    unsigned short* __restrict__ apout, const unsigned short* __restrict__ Wpack) {
  __shared__ __align__(16) unsigned short sh_S[NN][136];     // 17408 B
  __shared__ __align__(16) unsigned short sh_M0T[4][32][72]; // 18432 B
  __shared__ __align__(16) unsigned short sh_rbh[4][NN][8];  // 4096 B
  __shared__ __align__(16) unsigned short sh_ub[4][4][NN];   // 2048 B

  int blk = blockIdx.x;
  int b = blk >> 4, rp4 = blk & 15;
  int r0 = rp4 * 4;
  int tid = threadIdx.x;
  int w = tid >> 6, lane = tid & 63;
  int nlo = lane & 15, quad = lane >> 4;
  const short8 zero8 = {0, 0, 0, 0, 0, 0, 0, 0};

  f32x4 hbv[4][2];
#pragma unroll
  for (int mt = 0; mt < 4; ++mt)
#pragma unroll
    for (int nt = 0; nt < 2; ++nt)
#pragma unroll
      for (int reg = 0; reg < 4; ++reg)
        hbv[mt][nt][reg] =
            hA[((size_t)b * NN + mt * 16 + quad * 4 + reg) * HH + w * 32 + nt * 16 + nlo];

  const unsigned short* Wr1p = Wpack + WR1OFF;
  short8 bw[2];
#pragma unroll
  for (int nt = 0; nt < 2; ++nt)
    bw[nt] = *(const short8*)&Wr1p[((w * 32 + nt * 16 + nlo) * 4 + quad) * 8];
  const unsigned short* Bbase = Wpack;
  short8 bfr[4][2];
#pragma unroll
  for (int kt = 0; kt < 4; ++kt)
#pragma unroll
    for (int nt = 0; nt < 2; ++nt)
      bfr[kt][nt] = *(const short8*)&Bbase[((kt * 128 + w * 32 + nt * 16 + nlo) * 4 + quad) * 8];

  // ---- Stage A: all 4 receivers at once ----
  {
    int s = tid & 63;
    int ri4 = tid >> 6;
    int r = r0 + ri4;
    const float* pb = pos + b * NN * 3;
    float dx = pb[r * 3 + 0] - pb[s * 3 + 0];
    float dy = pb[r * 3 + 1] - pb[s * 3 + 1];
    float dz = pb[r * 3 + 2] - pb[s * 3 + 2];
    float rr = sqrtf(dx * dx + dy * dy + dz * dz + 1e-12f);
    float inv = __builtin_amdgcn_rcpf(rr);
    const float invAvg = 1.0f / 63.0f;
    float ia = inv * invAvg;
    sh_ub[ri4][0][s] = bf1(invAvg);
    sh_ub[ri4][1][s] = bf1(dx * ia);
    sh_ub[ri4][2][s] = bf1(dy * ia);
    sh_ub[ri4][3][s] = bf1(dz * ia);
    const float PI_OVER_5 = 0.628318530717958647692f;
    float fc = (s != r && rr < 5.0f) ? 0.5f * (__cosf(PI_OVER_5 * rr) + 1.0f) : 0.0f;
    float base = PI_OVER_5 * rr;
    float sc = inv * fc;
#pragma unroll
    for (int k0 = 0; k0 < 8; k0 += 4) {
      float v0 = __sinf((float)(k0 + 1) * base) * sc;
      float v1 = __sinf((float)(k0 + 2) * base) * sc;
      float v2 = __sinf((float)(k0 + 3) * base) * sc;
      float v3 = __sinf((float)(k0 + 4) * base) * sc;
      *(unsigned*)&sh_rbh[ri4][s][k0]     = bf2(v0, v1);
      *(unsigned*)&sh_rbh[ri4][s][k0 + 2] = bf2(v2, v3);
    }
  }
  __syncthreads();

#pragma unroll
  for (int rsel = 0; rsel < 4; ++rsel) {
    // ---- Stage B ----
#pragma unroll
    for (int mtp = 0; mtp < 2; ++mtp) {
      f32x4 Cs[2][2];
#pragma unroll
      for (int mi = 0; mi < 2; ++mi)
#pragma unroll
        for (int nt = 0; nt < 2; ++nt) Cs[mi][nt] = (f32x4){0.f, 0.f, 0.f, 0.f};
#pragma unroll
      for (int mi = 0; mi < 2; ++mi) {
        int mt = mtp * 2 + mi;
        short8 afr = (quad == 0) ? *(const short8*)&sh_rbh[rsel][mt * 16 + nlo][0] : zero8;
#pragma unroll
        for (int nt = 0; nt < 2; ++nt)
          Cs[mi][nt] = __builtin_amdgcn_mfma_f32_16x16x32_bf16(afr, bw[nt], Cs[mi][nt], 0, 0, 0);
      }
#pragma unroll
      for (int mi = 0; mi < 2; ++mi)
#pragma unroll
        for (int nt = 0; nt < 2; ++nt)
#pragma unroll
          for (int reg = 0; reg < 4; ++reg) {
            int s = (mtp * 2 + mi) * 16 + quad * 4 + reg;
            int c = w * 32 + nt * 16 + nlo;
            sh_S[s][c] = bf1(silu_f(Cs[mi][nt][reg]));
          }
    }
    __syncthreads();

    // ---- Main GEMM + M0T ----
#pragma unroll
    for (int mt = 0; mt < 4; ++mt) {
      short8 afr[4];
      int s_a = mt * 16 + nlo;
#pragma unroll
      for (int kt = 0; kt < 4; ++kt)
        afr[kt] = *(const short8*)&sh_S[s_a][kt * 32 + quad * 8];
#pragma unroll
      for (int nt = 0; nt < 2; ++nt) {
        f32x4 C = {0.f, 0.f, 0.f, 0.f};
#pragma unroll
        for (int kt = 0; kt < 4; ++kt)
          C = __builtin_amdgcn_mfma_f32_16x16x32_bf16(afr[kt], bfr[kt][nt], C, 0, 0, 0);
        f32x4 m0 = C * hbv[mt][nt];
        u32x2 pk;
        pk.x = bf2(m0[0], m0[1]);
        pk.y = bf2(m0[2], m0[3]);
        *(u32x2*)&sh_M0T[w][nt * 16 + nlo][mt * 16 + quad * 4] = pk;
      }
    }
    // ---- U-GEMM ----
    {
      short8 au[2];
#pragma unroll
      for (int kt = 0; kt < 2; ++kt)
        au[kt] = (nlo < 4) ? *(const short8*)&sh_ub[rsel][nlo][kt * 32 + quad * 8] : zero8;
      f32x4 Cu[2] = {{0, 0, 0, 0}, {0, 0, 0, 0}};
#pragma unroll
      for (int nt = 0; nt < 2; ++nt)
#pragma unroll
        for (int kt = 0; kt < 2; ++kt) {
          short8 bm = *(const short8*)&sh_M0T[w][nt * 16 + nlo][kt * 32 + quad * 8];
          Cu[nt] = __builtin_amdgcn_mfma_f32_16x16x32_bf16(au[kt], bm, Cu[nt], 0, 0, 0);
        }
      if (quad == 0) {
#pragma unroll
        for (int nt = 0; nt < 2; ++nt) {
          size_t base = (size_t)(b * NN + r0 + rsel) * HH + w * 32 + nt * 16 + nlo;
#pragma unroll
          for (int reg = 0; reg < 4; ++reg)
            apout[reg * PLANE + base] = bf1(Cu[nt][reg]);
        }
      }
    }
    if (rsel != 3) __syncthreads();
  }
}

// Fused layer-1 + update/readout. Grid 512: block blk = (b = blk>>3, u8 = blk&7)
// computes receivers [u8*8, u8*8+8) = rows [blk*8, blk*8+8), then updates/reads
// out those rows. Layer-1 planes 4-7 never touch global: produced into sh_a47
// (LDS) and consumed by the same block's update phase. Cross-block inputs (a0_l0,
// planes 0-3, hA) come from prior launches (launch-boundary coherent).
__global__ __launch_bounds__(256) void k_fused(
    const float* __restrict__ pos, const float* __restrict__ hA,
    unsigned short* __restrict__ apbf, const unsigned short* __restrict__ Wpack,
    const float* __restrict__ fs, float* __restrict__ out) {
  __shared__ __align__(16) unsigned char smem[50688];
  unsigned short (*sh_S)[136]      = (unsigned short (*)[136])smem;               // 17408 B
  unsigned short (*sh_M0T)[32][72] = (unsigned short (*)[32][72])(smem + 17408);  // 18432 B
  unsigned short (*sh_rbh)[NN][8]  = (unsigned short (*)[NN][8])(smem + 35840);   // 4096 B
  unsigned short (*sh_ub)[4][NN]   = (unsigned short (*)[4][NN])(smem + 39936);   // 2048 B
  unsigned short (*sh_a47)[8][136] = (unsigned short (*)[8][136])(smem + 41984);  // 8704 B

  int blk = blockIdx.x;
  int b = blk >> 3, u8 = blk & 7;
  int tid = threadIdx.x;
  int w = tid >> 6, lane = tid & 63;
  int nlo = lane & 15, quad = lane >> 4;
  const short8 zero8 = {0, 0, 0, 0, 0, 0, 0, 0};

  // ---- hbv: graph h in C-reg layout ----
  f32x4 hbv[4][2];
#pragma unroll
  for (int mt = 0; mt < 4; ++mt)
#pragma unroll
    for (int nt = 0; nt < 2; ++nt)
#pragma unroll
      for (int reg = 0; reg < 4; ++reg)
        hbv[mt][nt][reg] =
            hA[((size_t)b * NN + mt * 16 + quad * 4 + reg) * HH + w * 32 + nt * 16 + nlo];

  // ---- stage a0_l0 (prior launch) and apply hbv += a0_l0 @ Wupd0 ----
  for (int i = tid; i < NN * 64; i += 256) {
    int s = i >> 6, c2 = (i & 63) * 2;
    *(unsigned*)&sh_S[s][c2] =
        *(const unsigned*)&apbf[((size_t)b * NN + s) * HH + c2];
  }
  __syncthreads();
  {
    const unsigned short* Bu = Wpack + 2 * 16384;
#pragma unroll
    for (int mt = 0; mt < 4; ++mt) {
      short8 afr[4];
#pragma unroll
      for (int kt = 0; kt < 4; ++kt)
        afr[kt] = *(const short8*)&sh_S[mt * 16 + nlo][kt * 32 + quad * 8];
#pragma unroll
      for (int nt = 0; nt < 2; ++nt)
#pragma unroll
        for (int kt = 0; kt < 4; ++kt) {
          short8 bfr2 = *(const short8*)&Bu[((kt * 128 + w * 32 + nt * 16 + nlo) * 4 + quad) * 8];
          hbv[mt][nt] = __builtin_amdgcn_mfma_f32_16x16x32_bf16(afr[kt], bfr2, hbv[mt][nt], 0, 0, 0);
        }
    }
  }
  __syncthreads();   // sh_S reads done before Stage B overwrites

  // ---- layer-1 fragment hoists ----
  const unsigned short* Wr1p = Wpack + WR1OFF + 4096;
  short8 bw[2];
#pragma unroll
  for (int nt = 0; nt < 2; ++nt)
    bw[nt] = *(const short8*)&Wr1p[((w * 32 + nt * 16 + nlo) * 4 + quad) * 8];
  const unsigned short* Bbase = Wpack + 16384;
  short8 bfr[4][2];
#pragma unroll
  for (int kt = 0; kt < 4; ++kt)
#pragma unroll
    for (int nt = 0; nt < 2; ++nt)
      bfr[kt][nt] = *(const short8*)&Bbase[((kt * 128 + w * 32 + nt * 16 + nlo) * 4 + quad) * 8];

  for (int unit = 0; unit < 2; ++unit) {
    int r0 = u8 * 8 + unit * 4;

    // ---- Stage A: 4 receivers of this unit ----
    {
      int s = tid & 63;
      int ri4 = tid >> 6;
      int r = r0 + ri4;
      const float* pb = pos + b * NN * 3;
      float dx = pb[r * 3 + 0] - pb[s * 3 + 0];
      float dy = pb[r * 3 + 1] - pb[s * 3 + 1];
      float dz = pb[r * 3 + 2] - pb[s * 3 + 2];
      float rr = sqrtf(dx * dx + dy * dy + dz * dz + 1e-12f);
      float inv = __builtin_amdgcn_rcpf(rr);
      const float invAvg = 1.0f / 63.0f;
      float ia = inv * invAvg;
      sh_ub[ri4][0][s] = bf1(invAvg);
      sh_ub[ri4][1][s] = bf1(dx * ia);
      sh_ub[ri4][2][s] = bf1(dy * ia);
      sh_ub[ri4][3][s] = bf1(dz * ia);
      const float PI_OVER_5 = 0.628318530717958647692f;
      float fc = (s != r && rr < 5.0f) ? 0.5f * (__cosf(PI_OVER_5 * rr) + 1.0f) : 0.0f;
      float base = PI_OVER_5 * rr;
      float sc = inv * fc;
#pragma unroll
      for (int k0 = 0; k0 < 8; k0 += 4) {
        float v0 = __sinf((float)(k0 + 1) * base) * sc;
        float v1 = __sinf((float)(k0 + 2) * base) * sc;
        float v2 = __sinf((float)(k0 + 3) * base) * sc;
        float v3 = __sinf((float)(k0 + 4) * base) * sc;
        *(unsigned*)&sh_rbh[ri4][s][k0]     = bf2(v0, v1);
        *(unsigned*)&sh_rbh[ri4][s][k0 + 2] = bf2(v2, v3);
      }
    }
    __syncthreads();

#pragma unroll
    for (int rsel = 0; rsel < 4; ++rsel) {
      int lr = unit * 4 + rsel;   // local row 0..7
      // ---- Stage B ----
#pragma unroll
      for (int mtp = 0; mtp < 2; ++mtp) {
        f32x4 Cs[2][2];
#pragma unroll
        for (int mi = 0; mi < 2; ++mi)
#pragma unroll
          for (int nt = 0; nt < 2; ++nt) Cs[mi][nt] = (f32x4){0.f, 0.f, 0.f, 0.f};
#pragma unroll
        for (int mi = 0; mi < 2; ++mi) {
          int mt = mtp * 2 + mi;
          short8 afr = (quad == 0) ? *(const short8*)&sh_rbh[rsel][mt * 16 + nlo][0] : zero8;
#pragma unroll
          for (int nt = 0; nt < 2; ++nt)
            Cs[mi][nt] = __builtin_amdgcn_mfma_f32_16x16x32_bf16(afr, bw[nt], Cs[mi][nt], 0, 0, 0);
        }
#pragma unroll
        for (int mi = 0; mi < 2; ++mi)
#pragma unroll
          for (int nt = 0; nt < 2; ++nt)
#pragma unroll
            for (int reg = 0; reg < 4; ++reg) {
              int s = (mtp * 2 + mi) * 16 + quad * 4 + reg;
              int c = w * 32 + nt * 16 + nlo;
              sh_S[s][c] = bf1(silu_f(Cs[mi][nt][reg]));
            }
      }
      __syncthreads();

      // ---- Main GEMM + M0T ----
#pragma unroll
      for (int mt = 0; mt < 4; ++mt) {
        short8 afr[4];
        int s_a = mt * 16 + nlo;
#pragma unroll
        for (int kt = 0; kt < 4; ++kt)
          afr[kt] = *(const short8*)&sh_S[s_a][kt * 32 + quad * 8];
#pragma unroll
        for (int nt = 0; nt < 2; ++nt) {
          f32x4 C = {0.f, 0.f, 0.f, 0.f};
#pragma unroll
          for (int kt = 0; kt < 4; ++kt)
            C = __builtin_amdgcn_mfma_f32_16x16x32_bf16(afr[kt], bfr[kt][nt], C, 0, 0, 0);
          f32x4 m0 = C * hbv[mt][nt];
          u32x2 pk;
          pk.x = bf2(m0[0], m0[1]);
          pk.y = bf2(m0[2], m0[3]);
          *(u32x2*)&sh_M0T[w][nt * 16 + nlo][mt * 16 + quad * 4] = pk;
        }
      }
      // ---- U-GEMM -> sh_a47 (LDS only, no global) ----
      {
        short8 au[2];
#pragma unroll
        for (int kt = 0; kt < 2; ++kt)
          au[kt] = (nlo < 4) ? *(const short8*)&sh_ub[rsel][nlo][kt * 32 + quad * 8] : zero8;
        f32x4 Cu[2] = {{0, 0, 0, 0}, {0, 0, 0, 0}};
#pragma unroll
        for (int nt = 0; nt < 2; ++nt)
#pragma unroll
          for (int kt = 0; kt < 2; ++kt) {
            short8 bm = *(const short8*)&sh_M0T[w][nt * 16 + nlo][kt * 32 + quad * 8];
            Cu[nt] = __builtin_amdgcn_mfma_f32_16x16x32_bf16(au[kt], bm, Cu[nt], 0, 0, 0);
          }
        if (quad == 0) {
#pragma unroll
          for (int nt = 0; nt < 2; ++nt) {
            int c = w * 32 + nt * 16 + nlo;
#pragma unroll
            for (int reg = 0; reg < 4; ++reg)
              sh_a47[reg][lr][c] = bf1(Cu[nt][reg]);
          }
        }
      }
      __syncthreads();   // sh_S/rbh/ub safe to overwrite; a47 visible later
    }
  }

  // ---- update + readout for rows [blk*8, blk*8+8) ----
  {
    unsigned short (*sh_a03)[8][136] = (unsigned short (*)[8][136])smem;          // 8704 B
    unsigned short (*sh_h)[136]      = (unsigned short (*)[136])(smem + 8704);    // 2176 B
    float (*red)[8][3]               = (float (*)[8][3])(smem + 8704 + 2176);     // 384 B
    int row0 = blk * 8;
    for (int i = tid; i < 4 * 8 * 64; i += 256) {
      int p = i >> 9, rr = (i >> 6) & 7, c2 = (i & 63) * 2;
      *(unsigned*)&sh_a03[p][rr][c2] =
          *(const unsigned*)&apbf[p * PLANE + (size_t)(row0 + rr) * HH + c2];
    }
    f32x4 Ch[2];
#pragma unroll
    for (int nt = 0; nt < 2; ++nt)
#pragma unroll
      for (int reg = 0; reg < 4; ++reg)
        Ch[nt][reg] = (quad < 2)
            ? hA[(size_t)(row0 + quad * 4 + reg) * HH + w * 32 + nt * 16 + nlo] : 0.f;
    __syncthreads();
    gemm8(sh_a03[0], Wpack + 2 * 16384, w, nlo, quad, Ch);   // + a0l0@Wupd0
    gemm8(sh_a47[0], Wpack + 3 * 16384, w, nlo, quad, Ch);   // + a0l1@Wupd1
    f32x4 Cx[2] = {{0,0,0,0},{0,0,0,0}};
    f32x4 Cy[2] = {{0,0,0,0},{0,0,0,0}};
    f32x4 Cz[2] = {{0,0,0,0},{0,0,0,0}};
    gemm8(sh_a03[1], Wpack + 4 * 16384, w, nlo, quad, Cx);
    gemm8(sh_a47[1], Wpack + 5 * 16384, w, nlo, quad, Cx);
    gemm8(sh_a03[2], Wpack + 4 * 16384, w, nlo, quad, Cy);
    gemm8(sh_a47[2], Wpack + 5 * 16384, w, nlo, quad, Cy);
    gemm8(sh_a03[3], Wpack + 4 * 16384, w, nlo, quad, Cz);
    gemm8(sh_a47[3], Wpack + 5 * 16384, w, nlo, quad, Cz);
    if (quad < 2) {
#pragma unroll
      for (int nt = 0; nt < 2; ++nt)
#pragma unroll
        for (int reg = 0; reg < 4; ++reg)
          sh_h[quad * 4 + reg][w * 32 + nt * 16 + nlo] = bf1(Ch[nt][reg]);
    }
    __syncthreads();   // sh_h ready; sh_a03[0] free to alias
    unsigned short (*sh_q)[136] = sh_a03[0];
    f32x4 Cq[2] = {{0,0,0,0},{0,0,0,0}};
    gemm8(sh_h, Wpack + 6 * 16384, w, nlo, quad, Cq);
    if (quad < 2) {
#pragma unroll
      for (int nt = 0; nt < 2; ++nt)
#pragma unroll
        for (int reg = 0; reg < 4; ++reg)
          sh_q[quad * 4 + reg][w * 32 + nt * 16 + nlo] = bf1(silu_f(Cq[nt][reg]));
    }
    __syncthreads();
    f32x4 Cg[2] = {{0,0,0,0},{0,0,0,0}};
    gemm8(sh_q, Wpack + 7 * 16384, w, nlo, quad, Cg);
    float pr[3][4];
#pragma unroll
    for (int d = 0; d < 3; ++d)
#pragma unroll
      for (int reg = 0; reg < 4; ++reg) pr[d][reg] = 0.f;
#pragma unroll
    for (int nt = 0; nt < 2; ++nt)
#pragma unroll
      for (int reg = 0; reg < 4; ++reg) {
        float gv = Cg[nt][reg];
        pr[0][reg] += gv * Cx[nt][reg];
        pr[1][reg] += gv * Cy[nt][reg];
        pr[2][reg] += gv * Cz[nt][reg];
      }
#pragma unroll
    for (int off = 1; off < 16; off <<= 1)
#pragma unroll
      for (int d = 0; d < 3; ++d)
#pragma unroll
        for (int reg = 0; reg < 4; ++reg)
          pr[d][reg] += __shfl_xor(pr[d][reg], off);
    if (nlo == 0 && quad < 2) {
#pragma unroll
      for (int d = 0; d < 3; ++d)
#pragma unroll
        for (int reg = 0; reg < 4; ++reg)
          red[w][quad * 4 + reg][d] = pr[d][reg];
    }
    __syncthreads();
    if (tid < 24) {
      int row = tid / 3, d = tid % 3;
      float s = red[0][row][d] + red[1][row][d] + red[2][row][d] + red[3][row][d];
      out[(size_t)(row0 + row) * 3 + d] = s * fs[0];
    }
  }
}

extern "C" void kernel_launch(void* const* d_in, const int* in_sizes, int n_in,
                              void* d_out, int out_size, void* d_ws, size_t ws_size,
                              hipStream_t stream) {
  const float* pos  = (const float*)d_in[0];
  const int*   z    = (const int*)d_in[1];
  const float* gf   = (const float*)d_in[2];
  const float* emb  = (const float*)d_in[3];
  const float* Wt   = (const float*)d_in[4];
  const float* Wr1  = (const float*)d_in[5];
  const float* Wr2  = (const float*)d_in[6];
  const float* Wupd = (const float*)d_in[7];
  const float* Wmix = (const float*)d_in[8];
  const float* Wg1  = (const float*)d_in[9];
  const float* Wg2  = (const float*)d_in[10];
  const float* fs   = (const float*)d_in[11];
  float* out = (float*)d_out;

  float* ws = (float*)d_ws;
  float* hA = ws;                                         // 2 MB
  unsigned short* apbf = (unsigned short*)(ws + PLANE);   // bf16 planes (0-3 used)
  unsigned short* Wpack = (unsigned short*)(ws + 5 * PLANE);  // 272 KB

  k_init<<<dim3(256), dim3(256), 0, stream>>>(emb, z, gf, Wt, Wr1, Wr2, Wupd,
                                              Wmix, Wg1, Wg2, hA, Wpack);
  k_layer0<<<dim3(BB * 16), dim3(256), 0, stream>>>(pos, hA, apbf, Wpack);
  k_fused<<<dim3(512), dim3(256), 0, stream>>>(pos, hA, apbf, Wpack, fs, out);
}